// Round 1
// baseline (3517.274 us; speedup 1.0000x reference)
//
#include <hip/hip_runtime.h>
#include <hip/hip_bf16.h>

// Problem constants
constexpr int Cc = 256;     // channels
constexpr int NQ = 100;
constexpr int Bb = 8;
constexpr int HW = 64 * 64; // 4096 pixels per image
constexpr int G49 = 49;

// ---------------------------------------------------------------------------
// prep1: qq = (q+qpe)@Wq + bq ; qf1 = q@f1_w1 + f1_b1 ; geW1 = ge@W1l ; gef1 = ge@f1_w1
// grid 849 (800 query rows + 49 grid rows), block 256
// ---------------------------------------------------------------------------
__global__ void prep1_kernel(const float* __restrict__ q, const float* __restrict__ qpe,
                             const float* __restrict__ ge,
                             const float* __restrict__ Wq, const float* __restrict__ bq,
                             const float* __restrict__ f1_w1, const float* __restrict__ f1_b1,
                             const float* __restrict__ W1l,
                             float* __restrict__ qq, float* __restrict__ qf1,
                             float* __restrict__ geW1, float* __restrict__ gef1)
{
    __shared__ float s[Cc];
    __shared__ float rq[Cc];
    const int t = threadIdx.x;
    const int blk = blockIdx.x;
    if (blk < Bb * NQ) {
        float a = q[blk * Cc + t], p = qpe[blk * Cc + t];
        rq[t] = a; s[t] = a + p;
        __syncthreads();
        float acc1 = bq[t], acc2 = f1_b1[t];
        for (int k = 0; k < Cc; k++) {
            acc1 = fmaf(s[k],  Wq[k * Cc + t],    acc1);
            acc2 = fmaf(rq[k], f1_w1[k * Cc + t], acc2);
        }
        qq[blk * Cc + t]  = acc1;
        qf1[blk * Cc + t] = acc2;
    } else {
        int g = blk - Bb * NQ;
        s[t] = ge[g * Cc + t];
        __syncthreads();
        float acc1 = 0.f, acc2 = 0.f;
        for (int k = 0; k < Cc; k++) {
            acc1 = fmaf(s[k], W1l[k * Cc + t],   acc1);
            acc2 = fmaf(s[k], f1_w1[k * Cc + t], acc2);
        }
        geW1[g * Cc + t] = acc1;
        gef1[g * Cc + t] = acc2;
    }
}

// ---------------------------------------------------------------------------
// prep2: qk1 = qq@W1l + b1l   (grid 800, block 256)
// ---------------------------------------------------------------------------
__global__ void prep2_kernel(const float* __restrict__ qq, const float* __restrict__ W1l,
                             const float* __restrict__ b1l, float* __restrict__ qk1)
{
    __shared__ float s[Cc];
    const int t = threadIdx.x;
    const int blk = blockIdx.x;
    s[t] = qq[blk * Cc + t];
    __syncthreads();
    float acc = b1l[t];
    for (int k = 0; k < Cc; k++) acc = fmaf(s[k], W1l[k * Cc + t], acc);
    qk1[blk * Cc + t] = acc;
}

// ---------------------------------------------------------------------------
// conv: z[b,pix,c] = sum_cin (feat+pe)[b,cin,pix] * Wz[cin,c] + bz[c]  (bf16 out, channels-last)
//       fT[b,pix,c] = feat[b,c,pix]                                    (bf16 transpose)
// grid 1024 (= 8 batches * 128 pixel-tiles of 32), block 256, dyn LDS 73728 B
// ---------------------------------------------------------------------------
__global__ __launch_bounds__(256, 2) void conv_kernel(
    const float* __restrict__ feat, const float* __restrict__ feat_pe,
    const float* __restrict__ Wz, const float* __restrict__ bz,
    __hip_bfloat16* __restrict__ zT, __hip_bfloat16* __restrict__ fT)
{
    extern __shared__ char smem[];
    float (*sS)[36] = (float (*)[36])smem;              // feat+pe tile [256][36]
    float (*sF)[36] = (float (*)[36])(smem + 256 * 36 * 4); // feat tile

    const int t = threadIdx.x;
    const int blk = blockIdx.x;
    const int b = blk >> 7;
    const int pix0 = (blk & 127) * 32;

    const float* fp = feat    + ((size_t)(b * Cc + t)) * HW + pix0;
    const float* pp = feat_pe + ((size_t)(b * Cc + t)) * HW + pix0;
#pragma unroll
    for (int j = 0; j < 8; j++) {
        float4 f = *(const float4*)(fp + 4 * j);
        float4 p = *(const float4*)(pp + 4 * j);
        *(float4*)&sF[t][4 * j] = f;
        float4 sm; sm.x = f.x + p.x; sm.y = f.y + p.y; sm.z = f.z + p.z; sm.w = f.w + p.w;
        *(float4*)&sS[t][4 * j] = sm;
    }
    __syncthreads();

    float acc[32];
#pragma unroll
    for (int j = 0; j < 32; j++) acc[j] = 0.f;
    const float* Wc = Wz + t;
    for (int k = 0; k < Cc; k++) {
        float w = Wc[k * Cc];
#pragma unroll
        for (int j = 0; j < 8; j++) {
            float4 a = *(const float4*)&sS[k][4 * j];
            acc[4 * j + 0] = fmaf(a.x, w, acc[4 * j + 0]);
            acc[4 * j + 1] = fmaf(a.y, w, acc[4 * j + 1]);
            acc[4 * j + 2] = fmaf(a.z, w, acc[4 * j + 2]);
            acc[4 * j + 3] = fmaf(a.w, w, acc[4 * j + 3]);
        }
    }
    float bzt = bz[t];
    size_t obase = ((size_t)b * HW + pix0) * Cc + t;
#pragma unroll
    for (int px = 0; px < 32; px++) {
        zT[obase + (size_t)px * Cc] = __float2bfloat16(acc[px] + bzt);
        fT[obase + (size_t)px * Cc] = __float2bfloat16(sF[t][px]);
    }
}

// ---------------------------------------------------------------------------
// fused per-query pipeline.  grid 800, block 256, dyn LDS 100352 B (+ small static)
// Each thread owns output column t; acc[49] register accumulators per GEMM.
// ---------------------------------------------------------------------------
__device__ __forceinline__ void gemm49(const float (*__restrict__ src)[Cc],
                                       const float* __restrict__ W,
                                       float bias, int t, float* __restrict__ acc)
{
#pragma unroll
    for (int r = 0; r < G49; r++) acc[r] = bias;
    const float* Wc = W + t;
    float w0 = Wc[0], w1 = Wc[Cc], w2 = Wc[2 * Cc], w3 = Wc[3 * Cc];
    for (int k = 0; k < Cc; k += 4) {
        int kn = (k + 4) & 255;  // wraps on last iter (harmless prefetch)
        float nw0 = Wc[kn * Cc], nw1 = Wc[kn * Cc + Cc], nw2 = Wc[kn * Cc + 2 * Cc], nw3 = Wc[kn * Cc + 3 * Cc];
#pragma unroll
        for (int r = 0; r < G49; r++) {
            float4 a = *(const float4*)(&src[r][k]);
            acc[r] = fmaf(a.x, w0, acc[r]);
            acc[r] = fmaf(a.y, w1, acc[r]);
            acc[r] = fmaf(a.z, w2, acc[r]);
            acc[r] = fmaf(a.w, w3, acc[r]);
        }
        w0 = nw0; w1 = nw1; w2 = nw2; w3 = nw3;
    }
}

__device__ __forceinline__ void ln_rows(const float (*__restrict__ buf)[Cc],
                                        float* __restrict__ rmean, float* __restrict__ rrstd, int t)
{
    const int lane = t & 63, w = t >> 6;
    for (int r = w; r < G49; r += 4) {
        float a = buf[r][lane], b = buf[r][lane + 64], c = buf[r][lane + 128], d = buf[r][lane + 192];
        float s = a + b + c + d;
        float ss = a * a + b * b + c * c + d * d;
#pragma unroll
        for (int off = 32; off >= 1; off >>= 1) {
            s  += __shfl_xor(s, off);
            ss += __shfl_xor(ss, off);
        }
        if (lane == 0) {
            float m = s * (1.f / 256.f);
            float var = fmaxf(ss * (1.f / 256.f) - m * m, 0.f);
            rmean[r] = m;
            rrstd[r] = rsqrtf(var + 1e-5f);
        }
    }
}

__global__ __launch_bounds__(256, 1) void fused_kernel(
    const float* __restrict__ bboxes,
    const float* __restrict__ qk1, const float* __restrict__ qf1,
    const float* __restrict__ geW1, const float* __restrict__ gef1,
    const __hip_bfloat16* __restrict__ zT, const __hip_bfloat16* __restrict__ fT,
    const float* __restrict__ W2l, const float* __restrict__ b2l,
    const float* __restrict__ g1_w1, const float* __restrict__ g1_b1,
    const float* __restrict__ g1_w2, const float* __restrict__ g1_b2,
    const float* __restrict__ g1_g, const float* __restrict__ g1_beta,
    const float* __restrict__ g2_w1, const float* __restrict__ g2_b1,
    const float* __restrict__ g2_w2, const float* __restrict__ g2_b2,
    const float* __restrict__ g2_g, const float* __restrict__ g2_beta,
    const float* __restrict__ f1_w2, const float* __restrict__ f1_b2,
    const float* __restrict__ f2_w1, const float* __restrict__ f2_b1,
    const float* __restrict__ f2_w2, const float* __restrict__ f2_b2,
    const float* __restrict__ out_w, const float* __restrict__ out_b,
    const float* __restrict__ out_g, const float* __restrict__ out_beta,
    float* __restrict__ out)
{
    extern __shared__ char smem[];
    float (*bufA)[Cc] = (float (*)[Cc])smem;                      // 50176 B
    float (*bufB)[Cc] = (float (*)[Cc])(smem + G49 * Cc * 4);     // 50176 B

    __shared__ float qkrow[Cc], qfrow[Cc];
    __shared__ int   ti[G49][4];
    __shared__ float tw[G49][4];
    __shared__ float rmean[64], rrstd[64];

    const int t = threadIdx.x;
    const int qid = blockIdx.x;       // b*100 + nq
    const int b = qid / NQ;

    qkrow[t] = qk1[qid * Cc + t];
    qfrow[t] = qf1[qid * Cc + t];

    if (t < G49) {
        float bb0 = bboxes[qid * 4 + 0];
        float bb1 = bboxes[qid * 4 + 1];
        float bb2 = bboxes[qid * 4 + 2];
        float bb3 = bboxes[qid * 4 + 3];
        int s1 = t / 7, s2 = t % 7;
        float ys = bb2 * (1.f / 7.f) * ((float)s1 + 0.5f) + bb1 - 0.5f * bb2;
        float xs = bb3 * (1.f / 7.f) * ((float)s2 + 0.5f) + bb0 - 0.5f * bb3;
        float gx = fminf(fmaxf(2.f * xs - 1.f, -1.f), 1.f);
        float gy = fminf(fmaxf(2.f * ys - 1.f, -1.f), 1.f);
        float ix = ((gx + 1.f) * 64.f - 1.f) * 0.5f;
        float iy = ((gy + 1.f) * 64.f - 1.f) * 0.5f;
        float x0f = floorf(ix), y0f = floorf(iy);
        float wx1 = ix - x0f, wx0 = 1.f - wx1;
        float wy1 = iy - y0f, wy0 = 1.f - wy1;
        int x0 = (int)x0f, y0 = (int)y0f;
        int x1 = x0 + 1, y1 = y0 + 1;
        bool vx0 = (x0 >= 0) & (x0 < 64), vx1 = (x1 >= 0) & (x1 < 64);
        bool vy0 = (y0 >= 0) & (y0 < 64), vy1 = (y1 >= 0) & (y1 < 64);
        int cx0 = min(max(x0, 0), 63), cx1 = min(max(x1, 0), 63);
        int cy0 = min(max(y0, 0), 63), cy1 = min(max(y1, 0), 63);
        ti[t][0] = cy0 * 64 + cx0; tw[t][0] = (vx0 && vy0) ? wx0 * wy0 : 0.f;
        ti[t][1] = cy0 * 64 + cx1; tw[t][1] = (vx1 && vy0) ? wx1 * wy0 : 0.f;
        ti[t][2] = cy1 * 64 + cx0; tw[t][2] = (vx0 && vy1) ? wx0 * wy1 : 0.f;
        ti[t][3] = cy1 * 64 + cx1; tw[t][3] = (vx1 && vy1) ? wx1 * wy1 : 0.f;
    }
    __syncthreads();

    // --- sampling: bufA = roi_feat (from z), bufB = v (from feat) ---
    const __hip_bfloat16* zb = zT + (size_t)b * HW * Cc;
    const __hip_bfloat16* fb = fT + (size_t)b * HW * Cc;
    for (int r = 0; r < G49; r++) {
        float az = 0.f, av = 0.f;
#pragma unroll
        for (int p = 0; p < 4; p++) {
            float w = tw[r][p];
            int idx = ti[r][p];
            if (w != 0.f) {  // wave-uniform branch
                az += w * __bfloat162float(zb[(size_t)idx * Cc + t]);
                av += w * __bfloat162float(fb[(size_t)idx * Cc + t]);
            }
        }
        bufA[r][t] = az;
        bufB[r][t] = av;
    }
    __syncthreads();

    float acc[G49], m1r[G49], m2r[G49];

    // --- k = (qk1 + geW1) * (roi@W2l + b2l) -> bufA ---
    gemm49(bufA, W2l, b2l[t], t, acc);
    __syncthreads();
    {
        float qk_t = qkrow[t];
#pragma unroll
        for (int r = 0; r < G49; r++) bufA[r][t] = (qk_t + geW1[r * Cc + t]) * acc[r];
    }
    __syncthreads();

    // --- m2 = mlp(v; f2) : layer1 ---
    gemm49(bufB, f2_w1, f2_b1[t], t, acc);
    __syncthreads();
#pragma unroll
    for (int r = 0; r < G49; r++) bufB[r][t] = fmaxf(acc[r], 0.f);
    __syncthreads();
    gemm49(bufB, f2_w2, f2_b2[t], t, m2r);
    __syncthreads();

    // --- m1 = relu(qf1 + gef1) @ f1_w2 + f1_b2 ---
    {
        float qf_t = qfrow[t];
#pragma unroll
        for (int r = 0; r < G49; r++) bufB[r][t] = fmaxf(qf_t + gef1[r * Cc + t], 0.f);
    }
    __syncthreads();
    gemm49(bufB, f1_w2, f1_b2[t], t, m1r);
    __syncthreads();

    // --- gate1 = sigmoid(LN(mlp(k; g1))) ; fold into m1r ---
    gemm49(bufA, g1_w1, g1_b1[t], t, acc);
    __syncthreads();
#pragma unroll
    for (int r = 0; r < G49; r++) bufB[r][t] = fmaxf(acc[r], 0.f);
    __syncthreads();
    gemm49(bufB, g1_w2, g1_b2[t], t, acc);
    __syncthreads();
#pragma unroll
    for (int r = 0; r < G49; r++) bufB[r][t] = acc[r];
    __syncthreads();
    ln_rows(bufB, rmean, rrstd, t);
    __syncthreads();
    {
        float gg = g1_g[t], gb = g1_beta[t];
#pragma unroll
        for (int r = 0; r < G49; r++) {
            float u = (acc[r] - rmean[r]) * rrstd[r] * gg + gb;
            m1r[r] *= 1.f / (1.f + __expf(-u));
        }
    }

    // --- gate2 ; fold into m2r ---
    gemm49(bufA, g2_w1, g2_b1[t], t, acc);
    __syncthreads();
#pragma unroll
    for (int r = 0; r < G49; r++) bufB[r][t] = fmaxf(acc[r], 0.f);
    __syncthreads();
    gemm49(bufB, g2_w2, g2_b2[t], t, acc);
    __syncthreads();
#pragma unroll
    for (int r = 0; r < G49; r++) bufB[r][t] = acc[r];
    __syncthreads();
    ln_rows(bufB, rmean, rrstd, t);
    __syncthreads();
    {
        float gg = g2_g[t], gb = g2_beta[t];
#pragma unroll
        for (int r = 0; r < G49; r++) {
            float u = (acc[r] - rmean[r]) * rrstd[r] * gg + gb;
            m2r[r] *= 1.f / (1.f + __expf(-u));
        }
    }

    // --- out = gate1*m1 + gate2*m2 ; y = LN(out @ out_w + out_b) ---
#pragma unroll
    for (int r = 0; r < G49; r++) bufA[r][t] = m1r[r] + m2r[r];
    __syncthreads();
    gemm49(bufA, out_w, out_b[t], t, acc);
    __syncthreads();
#pragma unroll
    for (int r = 0; r < G49; r++) bufB[r][t] = acc[r];
    __syncthreads();
    ln_rows(bufB, rmean, rrstd, t);
    __syncthreads();
    {
        float gg = out_g[t], gb = out_beta[t];
        float* op = out + (size_t)qid * G49 * Cc;
#pragma unroll
        for (int r = 0; r < G49; r++) {
            op[r * Cc + t] = (acc[r] - rmean[r]) * rrstd[r] * gg + gb;
        }
    }
}

// ---------------------------------------------------------------------------
extern "C" void kernel_launch(void* const* d_in, const int* in_sizes, int n_in,
                              void* d_out, int out_size, void* d_ws, size_t ws_size,
                              hipStream_t stream)
{
    const float* q       = (const float*)d_in[0];
    const float* qpe     = (const float*)d_in[1];
    const float* feat    = (const float*)d_in[2];
    const float* feat_pe = (const float*)d_in[3];
    const float* bboxes  = (const float*)d_in[4];
    const float* ge      = (const float*)d_in[5];
    const float* Wz      = (const float*)d_in[6];
    const float* Wq      = (const float*)d_in[7];
    const float* W1l     = (const float*)d_in[8];
    const float* W2l     = (const float*)d_in[9];
    const float* g1_w1   = (const float*)d_in[10];
    const float* g1_w2   = (const float*)d_in[11];
    const float* g2_w1   = (const float*)d_in[12];
    const float* g2_w2   = (const float*)d_in[13];
    const float* f1_w1   = (const float*)d_in[14];
    const float* f1_w2   = (const float*)d_in[15];
    const float* f2_w1   = (const float*)d_in[16];
    const float* f2_w2   = (const float*)d_in[17];
    const float* out_w   = (const float*)d_in[18];
    const float* bz      = (const float*)d_in[19];
    const float* bq      = (const float*)d_in[20];
    const float* b1l     = (const float*)d_in[21];
    const float* b2l     = (const float*)d_in[22];
    const float* g1_b1   = (const float*)d_in[23];
    const float* g1_b2   = (const float*)d_in[24];
    const float* g2_b1   = (const float*)d_in[25];
    const float* g2_b2   = (const float*)d_in[26];
    const float* f1_b1   = (const float*)d_in[27];
    const float* f1_b2   = (const float*)d_in[28];
    const float* f2_b1   = (const float*)d_in[29];
    const float* f2_b2   = (const float*)d_in[30];
    const float* out_b   = (const float*)d_in[31];
    const float* g1_beta = (const float*)d_in[32];
    const float* g2_beta = (const float*)d_in[33];
    const float* out_beta= (const float*)d_in[34];
    const float* g1_g    = (const float*)d_in[35];
    const float* g2_g    = (const float*)d_in[36];
    const float* out_g   = (const float*)d_in[37];

    char* ws = (char*)d_ws;
    float* qqv  = (float*)(ws);                         // 800*256*4   = 819200
    float* qk1  = (float*)(ws + 819200);                // 819200
    float* qf1  = (float*)(ws + 1638400);               // 819200
    float* geW1 = (float*)(ws + 2457600);               // 50176
    float* gef1 = (float*)(ws + 2507776);               // 50176
    __hip_bfloat16* zT = (__hip_bfloat16*)(ws + 2557952);             // 8*4096*256*2 = 16777216
    __hip_bfloat16* fT = (__hip_bfloat16*)(ws + 2557952 + 16777216);  // 16777216  (total ~34.4 MB)

    prep1_kernel<<<dim3(Bb * NQ + G49), dim3(256), 0, stream>>>(
        q, qpe, ge, Wq, bq, f1_w1, f1_b1, W1l, qqv, qf1, geW1, gef1);

    conv_kernel<<<dim3(1024), dim3(256), 2 * 256 * 36 * 4, stream>>>(
        feat, feat_pe, Wz, bz, zT, fT);

    prep2_kernel<<<dim3(Bb * NQ), dim3(256), 0, stream>>>(qqv, W1l, b1l, qk1);

    fused_kernel<<<dim3(Bb * NQ), dim3(256), 2 * G49 * Cc * 4, stream>>>(
        bboxes, qk1, qf1, geW1, gef1, zT, fT,
        W2l, b2l,
        g1_w1, g1_b1, g1_w2, g1_b2, g1_g, g1_beta,
        g2_w1, g2_b1, g2_w2, g2_b2, g2_g, g2_beta,
        f1_w2, f1_b2, f2_w1, f2_b1, f2_w2, f2_b2,
        out_w, out_b, out_g, out_beta, (float*)d_out);
}

// Round 2
// 704.563 us; speedup vs baseline: 4.9921x; 4.9921x over previous
//
#include <hip/hip_runtime.h>
#include <hip/hip_bf16.h>

constexpr int Cc  = 256;
constexpr int NQ  = 100;
constexpr int Bb  = 8;
constexpr int HW  = 64 * 64;
constexpr int G49 = 49;

typedef __bf16 bf16x8 __attribute__((ext_vector_type(8)));
typedef float  f32x4  __attribute__((ext_vector_type(4)));

__device__ __forceinline__ float ldbf(const __hip_bfloat16* p) { return __bfloat162float(*p); }

__device__ __forceinline__ unsigned pk2(float a, float b) {
    union { unsigned u; __bf16 h[2]; } x;
    x.h[0] = (__bf16)a; x.h[1] = (__bf16)b;
    return x.u;
}
__device__ __forceinline__ float upk(unsigned u, int k) {
    union { unsigned u2; __bf16 h[2]; } x; x.u2 = u;
    return (float)x.h[k];
}

// swizzled bf16 LDS write: buffer layout [64 rows][256 cols] bf16, row stride 512B,
// byte ^= (row&7)<<4 (T2: spreads the 16-lane column-slice across 8 banks-of-16B)
__device__ __forceinline__ void lwb16(char* buf, int row, int col, float v) {
    int byte = (row * 512 + col * 2) ^ ((row & 7) << 4);
    *(__bf16*)(buf + byte) = (__bf16)v;
}

// ---------------------------------------------------------------------------
// prep1: qq=(q+qpe)@Wq+bq (LDS); qk1=qq@W1l+b1l ; qf1=q@f1_w1+f1_b1 ;
//        geW1=ge@W1l ; gef1=ge@f1_w1   (all outputs bf16)
// grid 849, block 256
// ---------------------------------------------------------------------------
__global__ void prep1_kernel(const float* __restrict__ q, const float* __restrict__ qpe,
                             const float* __restrict__ ge,
                             const float* __restrict__ Wq, const float* __restrict__ bq,
                             const float* __restrict__ W1l, const float* __restrict__ b1l,
                             const float* __restrict__ f1_w1, const float* __restrict__ f1_b1,
                             __hip_bfloat16* __restrict__ qk1, __hip_bfloat16* __restrict__ qf1,
                             __hip_bfloat16* __restrict__ geW1, __hip_bfloat16* __restrict__ gef1)
{
    __shared__ float s[Cc];
    __shared__ float rq[Cc];
    __shared__ float qqs[Cc];
    const int t = threadIdx.x;
    const int blk = blockIdx.x;
    if (blk < Bb * NQ) {
        float a = q[blk * Cc + t], p = qpe[blk * Cc + t];
        rq[t] = a; s[t] = a + p;
        __syncthreads();
        float acc1 = bq[t], acc2 = f1_b1[t];
        for (int k = 0; k < Cc; k++) {
            acc1 = fmaf(s[k],  Wq[k * Cc + t],    acc1);
            acc2 = fmaf(rq[k], f1_w1[k * Cc + t], acc2);
        }
        qqs[t] = acc1;
        qf1[blk * Cc + t] = __float2bfloat16(acc2);
        __syncthreads();
        float acc3 = b1l[t];
        for (int k = 0; k < Cc; k++) acc3 = fmaf(qqs[k], W1l[k * Cc + t], acc3);
        qk1[blk * Cc + t] = __float2bfloat16(acc3);
    } else {
        int g = blk - Bb * NQ;
        s[t] = ge[g * Cc + t];
        __syncthreads();
        float acc1 = 0.f, acc2 = 0.f;
        for (int k = 0; k < Cc; k++) {
            acc1 = fmaf(s[k], W1l[k * Cc + t],   acc1);
            acc2 = fmaf(s[k], f1_w1[k * Cc + t], acc2);
        }
        geW1[g * Cc + t] = __float2bfloat16(acc1);
        gef1[g * Cc + t] = __float2bfloat16(acc2);
    }
}

// ---------------------------------------------------------------------------
// wprep: transpose 9 weight matrices W[k][n] f32 -> WT[m][n][k] bf16
// grid (16, 9), block 256
// ---------------------------------------------------------------------------
__global__ void wprep_kernel(const float* __restrict__ W2l,
                             const float* __restrict__ g2w1, const float* __restrict__ g2w2,
                             const float* __restrict__ f2w1, const float* __restrict__ f2w2,
                             const float* __restrict__ g1w1, const float* __restrict__ g1w2,
                             const float* __restrict__ f1w2, const float* __restrict__ outw,
                             __hip_bfloat16* __restrict__ WT)
{
    __shared__ float ld[64][65];
    const float* srcs[9] = {W2l, g2w1, g2w2, f2w1, f2w2, g1w1, g1w2, f1w2, outw};
    const float* src = srcs[blockIdx.y];
    __hip_bfloat16* dst = WT + (size_t)blockIdx.y * Cc * Cc;
    const int t = threadIdx.x;
    const int k0 = (blockIdx.x >> 2) * 64, n0 = (blockIdx.x & 3) * 64;
#pragma unroll
    for (int j = 0; j < 16; j++) {
        int idx = j * 256 + t; int r = idx >> 6, c = idx & 63;
        ld[r][c] = src[(size_t)(k0 + r) * Cc + n0 + c];
    }
    __syncthreads();
#pragma unroll
    for (int j = 0; j < 16; j++) {
        int idx = j * 256 + t; int n = idx >> 6, k = idx & 63;
        dst[(size_t)(n0 + n) * Cc + k0 + k] = __float2bfloat16(ld[k][n]);
    }
}

// ---------------------------------------------------------------------------
// conv: z[b,pix,c] (bf16 channels-last) + fT transpose (unchanged from R1)
// ---------------------------------------------------------------------------
__global__ __launch_bounds__(256, 2) void conv_kernel(
    const float* __restrict__ feat, const float* __restrict__ feat_pe,
    const float* __restrict__ Wz, const float* __restrict__ bz,
    __hip_bfloat16* __restrict__ zT, __hip_bfloat16* __restrict__ fT)
{
    extern __shared__ char smem[];
    float (*sS)[36] = (float (*)[36])smem;
    float (*sF)[36] = (float (*)[36])(smem + 256 * 36 * 4);

    const int t = threadIdx.x;
    const int blk = blockIdx.x;
    const int b = blk >> 7;
    const int pix0 = (blk & 127) * 32;

    const float* fp = feat    + ((size_t)(b * Cc + t)) * HW + pix0;
    const float* pp = feat_pe + ((size_t)(b * Cc + t)) * HW + pix0;
#pragma unroll
    for (int j = 0; j < 8; j++) {
        float4 f = *(const float4*)(fp + 4 * j);
        float4 p = *(const float4*)(pp + 4 * j);
        *(float4*)&sF[t][4 * j] = f;
        float4 sm; sm.x = f.x + p.x; sm.y = f.y + p.y; sm.z = f.z + p.z; sm.w = f.w + p.w;
        *(float4*)&sS[t][4 * j] = sm;
    }
    __syncthreads();

    float acc[32];
#pragma unroll
    for (int j = 0; j < 32; j++) acc[j] = 0.f;
    const float* Wc = Wz + t;
    for (int k = 0; k < Cc; k++) {
        float w = Wc[k * Cc];
#pragma unroll
        for (int j = 0; j < 8; j++) {
            float4 a = *(const float4*)&sS[k][4 * j];
            acc[4 * j + 0] = fmaf(a.x, w, acc[4 * j + 0]);
            acc[4 * j + 1] = fmaf(a.y, w, acc[4 * j + 1]);
            acc[4 * j + 2] = fmaf(a.z, w, acc[4 * j + 2]);
            acc[4 * j + 3] = fmaf(a.w, w, acc[4 * j + 3]);
        }
    }
    float bzt = bz[t];
    size_t obase = ((size_t)b * HW + pix0) * Cc + t;
#pragma unroll
    for (int px = 0; px < 32; px++) {
        zT[obase + (size_t)px * Cc] = __float2bfloat16(acc[px] + bzt);
        fT[obase + (size_t)px * Cc] = __float2bfloat16(sF[t][px]);
    }
}

// ---------------------------------------------------------------------------
// MFMA GEMM core: acc[16] (f32x4) = A(LDS, 64x256 bf16 swizzled) @ WT_m + bias
// wave w owns cols [w*64, w*64+64).  Layouts (gfx950 mfma_f32_16x16x32_bf16):
//   A frag: lane l -> row l&15, k = (l>>4)*8 + j
//   B frag: lane l -> col l&15, k = (l>>4)*8 + j      (WT is [n][k] bf16)
//   C frag: reg i, lane l -> row (l>>4)*4 + i, col l&15    [verified m89]
// ---------------------------------------------------------------------------
__device__ __forceinline__ void run_gemm(const char* __restrict__ Abuf,
                                         const __bf16* __restrict__ Wt,
                                         const float* __restrict__ bias,
                                         int l15, int lhi, int n0, f32x4* acc)
{
#pragma unroll
    for (int nt = 0; nt < 4; nt++) {
        float bv = bias ? bias[n0 + nt * 16 + l15] : 0.f;
        f32x4 v = {bv, bv, bv, bv};
        acc[0 * 4 + nt] = v; acc[1 * 4 + nt] = v; acc[2 * 4 + nt] = v; acc[3 * 4 + nt] = v;
    }
#pragma unroll
    for (int ks = 0; ks < 8; ks++) {
        bf16x8 bfr[4], afr[4];
#pragma unroll
        for (int nt = 0; nt < 4; nt++)
            bfr[nt] = *(const bf16x8*)(Wt + (size_t)(n0 + nt * 16 + l15) * Cc + ks * 32 + lhi * 8);
#pragma unroll
        for (int mt = 0; mt < 4; mt++) {
            int row = mt * 16 + l15;
            int byte = (row * 512 + (ks * 32 + lhi * 8) * 2) ^ ((row & 7) << 4);
            afr[mt] = *(const bf16x8*)(Abuf + byte);
        }
#pragma unroll
        for (int mt = 0; mt < 4; mt++)
#pragma unroll
            for (int nt = 0; nt < 4; nt++)
                acc[mt * 4 + nt] = __builtin_amdgcn_mfma_f32_16x16x32_bf16(
                    afr[mt], bfr[nt], acc[mt * 4 + nt], 0, 0, 0);
    }
}

// LN stats over rows from C frags: per lane 16 rows x (sum over its 4 nt cols),
// 4-step shfl_xor over lanes 0..15, cross-wave combine in LDS.
__device__ __forceinline__ void ln_stats(const f32x4* acc, int l15, int lhi, int w, int t,
                                         float* sred, float* smv)
{
    float s[16], qq[16];
#pragma unroll
    for (int mt = 0; mt < 4; mt++)
#pragma unroll
        for (int i = 0; i < 4; i++) {
            float a = acc[mt * 4 + 0][i], b = acc[mt * 4 + 1][i];
            float c = acc[mt * 4 + 2][i], d = acc[mt * 4 + 3][i];
            s[mt * 4 + i]  = a + b + c + d;
            qq[mt * 4 + i] = a * a + b * b + c * c + d * d;
        }
#pragma unroll
    for (int off = 1; off < 16; off <<= 1)
#pragma unroll
        for (int j = 0; j < 16; j++) {
            s[j]  += __shfl_xor(s[j],  off);
            qq[j] += __shfl_xor(qq[j], off);
        }
    if (l15 == 0) {
#pragma unroll
        for (int mt = 0; mt < 4; mt++)
#pragma unroll
            for (int i = 0; i < 4; i++) {
                int row = mt * 16 + lhi * 4 + i;
                sred[(row * 4 + w) * 2]     = s[mt * 4 + i];
                sred[(row * 4 + w) * 2 + 1] = qq[mt * 4 + i];
            }
    }
    __syncthreads();
    if (t < 64) {
        float ts = sred[(t * 4 + 0) * 2] + sred[(t * 4 + 1) * 2]
                 + sred[(t * 4 + 2) * 2] + sred[(t * 4 + 3) * 2];
        float tq = sred[(t * 4 + 0) * 2 + 1] + sred[(t * 4 + 1) * 2 + 1]
                 + sred[(t * 4 + 2) * 2 + 1] + sred[(t * 4 + 3) * 2 + 1];
        float m = ts * (1.f / 256.f);
        float var = fmaxf(tq * (1.f / 256.f) - m * m, 0.f);
        smv[t * 2]     = m;
        smv[t * 2 + 1] = rsqrtf(var + 1e-5f);
    }
    __syncthreads();
}

__device__ __forceinline__ void gate_apply(const f32x4* acc, const float* __restrict__ g,
                                           const float* __restrict__ bet, const float* smv,
                                           int n0, int l15, int lhi, unsigned* gp)
{
#pragma unroll
    for (int nt = 0; nt < 4; nt++) {
        int col = n0 + nt * 16 + l15;
        float gg = g[col], gb = bet[col];
#pragma unroll
        for (int mt = 0; mt < 4; mt++) {
            float gv[4];
#pragma unroll
            for (int i = 0; i < 4; i++) {
                int row = mt * 16 + lhi * 4 + i;
                float u = (acc[mt * 4 + nt][i] - smv[row * 2]) * smv[row * 2 + 1] * gg + gb;
                gv[i] = 1.f / (1.f + __expf(-u));
            }
            gp[(mt * 4 + nt) * 2]     = pk2(gv[0], gv[1]);
            gp[(mt * 4 + nt) * 2 + 1] = pk2(gv[2], gv[3]);
        }
    }
}

// ---------------------------------------------------------------------------
// fused: per-query MFMA pipeline. grid 800, block 256 (4 waves), dyn LDS 64KB.
// ---------------------------------------------------------------------------
__global__ __launch_bounds__(256, 2) void fused_kernel(
    const float* __restrict__ bboxes,
    const __hip_bfloat16* __restrict__ qk1, const __hip_bfloat16* __restrict__ qf1,
    const __hip_bfloat16* __restrict__ geW1, const __hip_bfloat16* __restrict__ gef1,
    const __hip_bfloat16* __restrict__ zT, const __hip_bfloat16* __restrict__ fT,
    const __hip_bfloat16* __restrict__ WT,
    const float* __restrict__ b2l,
    const float* __restrict__ g1_b1, const float* __restrict__ g1_b2,
    const float* __restrict__ g1_g,  const float* __restrict__ g1_beta,
    const float* __restrict__ g2_b1, const float* __restrict__ g2_b2,
    const float* __restrict__ g2_g,  const float* __restrict__ g2_beta,
    const float* __restrict__ f1_b2,
    const float* __restrict__ f2_b1, const float* __restrict__ f2_b2,
    const float* __restrict__ out_b, const float* __restrict__ out_g,
    const float* __restrict__ out_beta,
    float* __restrict__ out)
{
    extern __shared__ char smem[];
    char* bufA = smem;            // k buffer   [64][256] bf16 swizzled
    char* bufB = smem + 32768;    // roi/v/intermediates

    __shared__ int   ti[G49][4];
    __shared__ float tw[G49][4];
    __shared__ float sred[64 * 4 * 2];
    __shared__ float smv[64 * 2];

    const int t = threadIdx.x;
    const int lane = t & 63;
    const int w = t >> 6;          // wave id, owns cols [w*64, w*64+64)
    const int n0 = w * 64;
    const int l15 = lane & 15, lhi = lane >> 4;
    const int qid = blockIdx.x;
    const int b = qid / NQ;

    const __bf16* WT_W2l  = (const __bf16*)WT + 0 * Cc * Cc;
    const __bf16* WT_g2w1 = (const __bf16*)WT + 1 * Cc * Cc;
    const __bf16* WT_g2w2 = (const __bf16*)WT + 2 * Cc * Cc;
    const __bf16* WT_f2w1 = (const __bf16*)WT + 3 * Cc * Cc;
    const __bf16* WT_f2w2 = (const __bf16*)WT + 4 * Cc * Cc;
    const __bf16* WT_g1w1 = (const __bf16*)WT + 5 * Cc * Cc;
    const __bf16* WT_g1w2 = (const __bf16*)WT + 6 * Cc * Cc;
    const __bf16* WT_f1w2 = (const __bf16*)WT + 7 * Cc * Cc;
    const __bf16* WT_outw = (const __bf16*)WT + 8 * Cc * Cc;

    // --- bilinear tap setup ---
    if (t < G49) {
        float bb0 = bboxes[qid * 4 + 0];
        float bb1 = bboxes[qid * 4 + 1];
        float bb2 = bboxes[qid * 4 + 2];
        float bb3 = bboxes[qid * 4 + 3];
        int s1 = t / 7, s2 = t % 7;
        float ys = bb2 * (1.f / 7.f) * ((float)s1 + 0.5f) + bb1 - 0.5f * bb2;
        float xs = bb3 * (1.f / 7.f) * ((float)s2 + 0.5f) + bb0 - 0.5f * bb3;
        float gx = fminf(fmaxf(2.f * xs - 1.f, -1.f), 1.f);
        float gy = fminf(fmaxf(2.f * ys - 1.f, -1.f), 1.f);
        float ix = ((gx + 1.f) * 64.f - 1.f) * 0.5f;
        float iy = ((gy + 1.f) * 64.f - 1.f) * 0.5f;
        float x0f = floorf(ix), y0f = floorf(iy);
        float wx1 = ix - x0f, wx0 = 1.f - wx1;
        float wy1 = iy - y0f, wy0 = 1.f - wy1;
        int x0 = (int)x0f, y0 = (int)y0f;
        int x1 = x0 + 1, y1 = y0 + 1;
        bool vx0 = (x0 >= 0) & (x0 < 64), vx1 = (x1 >= 0) & (x1 < 64);
        bool vy0 = (y0 >= 0) & (y0 < 64), vy1 = (y1 >= 0) & (y1 < 64);
        int cx0 = min(max(x0, 0), 63), cx1 = min(max(x1, 0), 63);
        int cy0 = min(max(y0, 0), 63), cy1 = min(max(y1, 0), 63);
        ti[t][0] = cy0 * 64 + cx0; tw[t][0] = (vx0 && vy0) ? wx0 * wy0 : 0.f;
        ti[t][1] = cy0 * 64 + cx1; tw[t][1] = (vx1 && vy0) ? wx1 * wy0 : 0.f;
        ti[t][2] = cy1 * 64 + cx0; tw[t][2] = (vx0 && vy1) ? wx0 * wy1 : 0.f;
        ti[t][3] = cy1 * 64 + cx1; tw[t][3] = (vx1 && vy1) ? wx1 * wy1 : 0.f;
    }
    // zero pad rows of bufB once (only NaN-risk: uninitialized LDS)
    for (int r = G49; r < 64; r++) lwb16(bufB, r, t, 0.f);
    __syncthreads();

    // --- sample roi (from z) -> bufB ---
    {
        const __hip_bfloat16* zb = zT + (size_t)b * HW * Cc;
        for (int r = 0; r < G49; r++) {
            float az = 0.f;
#pragma unroll
            for (int p = 0; p < 4; p++) {
                float wt_ = tw[r][p];
                if (wt_ != 0.f) az += wt_ * ldbf(&zb[(size_t)ti[r][p] * Cc + t]);
            }
            lwb16(bufB, r, t, az);
        }
    }
    __syncthreads();

    f32x4 acc[16];

    // --- G1: roi @ W2l + b2l ; k = (qk1+geW1)*acc -> bufA ---
    run_gemm(bufB, WT_W2l, b2l, l15, lhi, n0, acc);
#pragma unroll
    for (int nt = 0; nt < 4; nt++) {
        int col = n0 + nt * 16 + l15;
        float qk = ldbf(&qk1[qid * Cc + col]);
#pragma unroll
        for (int mt = 0; mt < 4; mt++)
#pragma unroll
            for (int i = 0; i < 4; i++) {
                int row = mt * 16 + lhi * 4 + i;
                float gw = (row < G49) ? ldbf(&geW1[row * Cc + col]) : 0.f;
                lwb16(bufA, row, col, (qk + gw) * acc[mt * 4 + nt][i]);
            }
    }
    __syncthreads();

    // --- G4: k @ g2_w1 -> relu -> bufB ---
    run_gemm(bufA, WT_g2w1, g2_b1, l15, lhi, n0, acc);
    __syncthreads();
#pragma unroll
    for (int nt = 0; nt < 4; nt++)
#pragma unroll
        for (int mt = 0; mt < 4; mt++)
#pragma unroll
            for (int i = 0; i < 4; i++)
                lwb16(bufB, mt * 16 + lhi * 4 + i, n0 + nt * 16 + l15,
                      fmaxf(acc[mt * 4 + nt][i], 0.f));
    __syncthreads();

    // --- G5: @ g2_w2 ; LN ; gate2 ---
    run_gemm(bufB, WT_g2w2, g2_b2, l15, lhi, n0, acc);
    ln_stats(acc, l15, lhi, w, t, sred, smv);
    unsigned g2p[32];
    gate_apply(acc, g2_g, g2_beta, smv, n0, l15, lhi, g2p);

    // --- sample v (from feat) -> bufB ---   (G5 reads done via ln_stats barriers)
    {
        const __hip_bfloat16* fb = fT + (size_t)b * HW * Cc;
        for (int r = 0; r < G49; r++) {
            float av = 0.f;
#pragma unroll
            for (int p = 0; p < 4; p++) {
                float wt_ = tw[r][p];
                if (wt_ != 0.f) av += wt_ * ldbf(&fb[(size_t)ti[r][p] * Cc + t]);
            }
            lwb16(bufB, r, t, av);
        }
    }
    __syncthreads();

    // --- G2: v @ f2_w1 -> relu -> bufB (in place) ---
    run_gemm(bufB, WT_f2w1, f2_b1, l15, lhi, n0, acc);
    __syncthreads();
#pragma unroll
    for (int nt = 0; nt < 4; nt++)
#pragma unroll
        for (int mt = 0; mt < 4; mt++)
#pragma unroll
            for (int i = 0; i < 4; i++)
                lwb16(bufB, mt * 16 + lhi * 4 + i, n0 + nt * 16 + l15,
                      fmaxf(acc[mt * 4 + nt][i], 0.f));
    __syncthreads();

    // --- G3: @ f2_w2 ; comb = gate2 * m2 (packed regs) ---
    run_gemm(bufB, WT_f2w2, f2_b2, l15, lhi, n0, acc);
    __syncthreads();   // all G3 reads of bufB done before G7 epi overwrites it
    unsigned comb[32];
#pragma unroll
    for (int j = 0; j < 16; j++) {
        comb[j * 2]     = pk2(upk(g2p[j * 2], 0) * acc[j][0], upk(g2p[j * 2], 1) * acc[j][1]);
        comb[j * 2 + 1] = pk2(upk(g2p[j * 2 + 1], 0) * acc[j][2], upk(g2p[j * 2 + 1], 1) * acc[j][3]);
    }

    // --- G7: k @ g1_w1 -> relu -> bufB ---
    run_gemm(bufA, WT_g1w1, g1_b1, l15, lhi, n0, acc);
#pragma unroll
    for (int nt = 0; nt < 4; nt++)
#pragma unroll
        for (int mt = 0; mt < 4; mt++)
#pragma unroll
            for (int i = 0; i < 4; i++)
                lwb16(bufB, mt * 16 + lhi * 4 + i, n0 + nt * 16 + l15,
                      fmaxf(acc[mt * 4 + nt][i], 0.f));
    __syncthreads();

    // --- G8: @ g1_w2 ; LN ; gate1 ---
    run_gemm(bufB, WT_g1w2, g1_b2, l15, lhi, n0, acc);
    ln_stats(acc, l15, lhi, w, t, sred, smv);
    unsigned g1p[32];
    gate_apply(acc, g1_g, g1_beta, smv, n0, l15, lhi, g1p);

    // --- m1 layer1 (no GEMM): relu(qf1[col] + gef1[row][col]) -> bufB ---
    {
        float qf = ldbf(&qf1[qid * Cc + t]);
        for (int r = 0; r < 64; r++) {
            int rr = r < G49 ? r : 0;
            lwb16(bufB, r, t, fmaxf(qf + ldbf(&gef1[rr * Cc + t]), 0.f));
        }
    }
    __syncthreads();

    // --- G6: @ f1_w2 ; final = comb + gate1*m1 -> bufB (in place) ---
    run_gemm(bufB, WT_f1w2, f1_b2, l15, lhi, n0, acc);
    __syncthreads();
#pragma unroll
    for (int nt = 0; nt < 4; nt++)
#pragma unroll
        for (int mt = 0; mt < 4; mt++)
#pragma unroll
            for (int i = 0; i < 4; i++) {
                int j = mt * 4 + nt;
                int hw_ = i >> 1, lo = i & 1;
                float f = upk(comb[j * 2 + hw_], lo) + upk(g1p[j * 2 + hw_], lo) * acc[j][i];
                lwb16(bufB, mt * 16 + lhi * 4 + i, n0 + nt * 16 + l15, f);
            }
    __syncthreads();

    // --- G9: @ out_w ; LN ; store ---
    run_gemm(bufB, WT_outw, out_b, l15, lhi, n0, acc);
    ln_stats(acc, l15, lhi, w, t, sred, smv);
#pragma unroll
    for (int nt = 0; nt < 4; nt++) {
        int col = n0 + nt * 16 + l15;
        float gg = out_g[col], gb = out_beta[col];
#pragma unroll
        for (int mt = 0; mt < 4; mt++)
#pragma unroll
            for (int i = 0; i < 4; i++) {
                int row = mt * 16 + lhi * 4 + i;
                if (row < G49)
                    out[((size_t)qid * G49 + row) * Cc + col] =
                        (acc[mt * 4 + nt][i] - smv[row * 2]) * smv[row * 2 + 1] * gg + gb;
            }
    }
}

// ---------------------------------------------------------------------------
extern "C" void kernel_launch(void* const* d_in, const int* in_sizes, int n_in,
                              void* d_out, int out_size, void* d_ws, size_t ws_size,
                              hipStream_t stream)
{
    const float* q       = (const float*)d_in[0];
    const float* qpe     = (const float*)d_in[1];
    const float* feat    = (const float*)d_in[2];
    const float* feat_pe = (const float*)d_in[3];
    const float* bboxes  = (const float*)d_in[4];
    const float* ge      = (const float*)d_in[5];
    const float* Wz      = (const float*)d_in[6];
    const float* Wq      = (const float*)d_in[7];
    const float* W1l     = (const float*)d_in[8];
    const float* W2l     = (const float*)d_in[9];
    const float* g1_w1   = (const float*)d_in[10];
    const float* g1_w2   = (const float*)d_in[11];
    const float* g2_w1   = (const float*)d_in[12];
    const float* g2_w2   = (const float*)d_in[13];
    const float* f1_w1   = (const float*)d_in[14];
    const float* f1_w2   = (const float*)d_in[15];
    const float* f2_w1   = (const float*)d_in[16];
    const float* f2_w2   = (const float*)d_in[17];
    const float* out_w   = (const float*)d_in[18];
    const float* bz      = (const float*)d_in[19];
    const float* bq      = (const float*)d_in[20];
    const float* b1l     = (const float*)d_in[21];
    const float* b2l     = (const float*)d_in[22];
    const float* g1_b1   = (const float*)d_in[23];
    const float* g1_b2   = (const float*)d_in[24];
    const float* g2_b1   = (const float*)d_in[25];
    const float* g2_b2   = (const float*)d_in[26];
    const float* f1_b1   = (const float*)d_in[27];
    const float* f1_b2   = (const float*)d_in[28];
    const float* f2_b1   = (const float*)d_in[29];
    const float* f2_b2   = (const float*)d_in[30];
    const float* out_b   = (const float*)d_in[31];
    const float* g1_beta = (const float*)d_in[32];
    const float* g2_beta = (const float*)d_in[33];
    const float* out_beta= (const float*)d_in[34];
    const float* g1_g    = (const float*)d_in[35];
    const float* g2_g    = (const float*)d_in[36];
    const float* out_g   = (const float*)d_in[37];

    // ws layout (bf16 throughout; total 35,603,456 B < proven 36.1MB)
    char* ws = (char*)d_ws;
    __hip_bfloat16* qk1  = (__hip_bfloat16*)(ws);                 // 409600
    __hip_bfloat16* qf1  = (__hip_bfloat16*)(ws + 409600);        // 409600
    __hip_bfloat16* geW1 = (__hip_bfloat16*)(ws + 819200);        // 25088
    __hip_bfloat16* gef1 = (__hip_bfloat16*)(ws + 844288);        // 25088
    __hip_bfloat16* WT   = (__hip_bfloat16*)(ws + 869376);        // 1179648
    __hip_bfloat16* zT   = (__hip_bfloat16*)(ws + 2049024);       // 16777216
    __hip_bfloat16* fT   = (__hip_bfloat16*)(ws + 18826240);      // 16777216

    prep1_kernel<<<dim3(Bb * NQ + G49), dim3(256), 0, stream>>>(
        q, qpe, ge, Wq, bq, W1l, b1l, f1_w1, f1_b1, qk1, qf1, geW1, gef1);

    wprep_kernel<<<dim3(16, 9), dim3(256), 0, stream>>>(
        W2l, g2_w1, g2_w2, f2_w1, f2_w2, g1_w1, g1_w2, f1_w2, out_w, WT);

    conv_kernel<<<dim3(1024), dim3(256), 2 * 256 * 36 * 4, stream>>>(
        feat, feat_pe, Wz, bz, zT, fT);

    fused_kernel<<<dim3(Bb * NQ), dim3(256), 65536, stream>>>(
        bboxes, qk1, qf1, geW1, gef1, zT, fT, WT,
        b2l,
        g1_b1, g1_b2, g1_g, g1_beta,
        g2_b1, g2_b2, g2_g, g2_beta,
        f1_b2, f2_b1, f2_b2,
        out_b, out_g, out_beta, (float*)d_out);
}

// Round 5
// 687.811 us; speedup vs baseline: 5.1137x; 1.0244x over previous
//
#include <hip/hip_runtime.h>
#include <hip/hip_bf16.h>

constexpr int Cc  = 256;
constexpr int NQ  = 100;
constexpr int Bb  = 8;
constexpr int HW  = 64 * 64;
constexpr int G49 = 49;

typedef __bf16 bf16x8 __attribute__((ext_vector_type(8)));
typedef float  f32x4  __attribute__((ext_vector_type(4)));

__device__ __forceinline__ float ldbf(const __hip_bfloat16* p) { return __bfloat162float(*p); }

__device__ __forceinline__ unsigned pk2(float a, float b) {
    union { unsigned u; __bf16 h[2]; } x;
    x.h[0] = (__bf16)a; x.h[1] = (__bf16)b;
    return x.u;
}
__device__ __forceinline__ float upk(unsigned u, int k) {
    union { unsigned u2; __bf16 h[2]; } x; x.u2 = u;
    return (float)x.h[k];
}

// swizzled bf16 LDS write: buffer [64 rows][256 cols] bf16, row stride 512B,
// byte ^= (row&7)<<4 (T2 swizzle)
__device__ __forceinline__ void lwb16(char* buf, int row, int col, float v) {
    int byte = (row * 512 + col * 2) ^ ((row & 7) << 4);
    *(__bf16*)(buf + byte) = (__bf16)v;
}

// ---------------------------------------------------------------------------
// prep1 (unchanged from R2)
// ---------------------------------------------------------------------------
__global__ void prep1_kernel(const float* __restrict__ q, const float* __restrict__ qpe,
                             const float* __restrict__ ge,
                             const float* __restrict__ Wq, const float* __restrict__ bq,
                             const float* __restrict__ W1l, const float* __restrict__ b1l,
                             const float* __restrict__ f1_w1, const float* __restrict__ f1_b1,
                             __hip_bfloat16* __restrict__ qk1, __hip_bfloat16* __restrict__ qf1,
                             __hip_bfloat16* __restrict__ geW1, __hip_bfloat16* __restrict__ gef1)
{
    __shared__ float s[Cc];
    __shared__ float rq[Cc];
    __shared__ float qqs[Cc];
    const int t = threadIdx.x;
    const int blk = blockIdx.x;
    if (blk < Bb * NQ) {
        float a = q[blk * Cc + t], p = qpe[blk * Cc + t];
        rq[t] = a; s[t] = a + p;
        __syncthreads();
        float acc1 = bq[t], acc2 = f1_b1[t];
        for (int k = 0; k < Cc; k++) {
            acc1 = fmaf(s[k],  Wq[k * Cc + t],    acc1);
            acc2 = fmaf(rq[k], f1_w1[k * Cc + t], acc2);
        }
        qqs[t] = acc1;
        qf1[blk * Cc + t] = __float2bfloat16(acc2);
        __syncthreads();
        float acc3 = b1l[t];
        for (int k = 0; k < Cc; k++) acc3 = fmaf(qqs[k], W1l[k * Cc + t], acc3);
        qk1[blk * Cc + t] = __float2bfloat16(acc3);
    } else {
        int g = blk - Bb * NQ;
        s[t] = ge[g * Cc + t];
        __syncthreads();
        float acc1 = 0.f, acc2 = 0.f;
        for (int k = 0; k < Cc; k++) {
            acc1 = fmaf(s[k], W1l[k * Cc + t],   acc1);
            acc2 = fmaf(s[k], f1_w1[k * Cc + t], acc2);
        }
        geW1[g * Cc + t] = __float2bfloat16(acc1);
        gef1[g * Cc + t] = __float2bfloat16(acc2);
    }
}

// ---------------------------------------------------------------------------
// wprep (unchanged from R2)
// ---------------------------------------------------------------------------
__global__ void wprep_kernel(const float* __restrict__ W2l,
                             const float* __restrict__ g2w1, const float* __restrict__ g2w2,
                             const float* __restrict__ f2w1, const float* __restrict__ f2w2,
                             const float* __restrict__ g1w1, const float* __restrict__ g1w2,
                             const float* __restrict__ f1w2, const float* __restrict__ outw,
                             __hip_bfloat16* __restrict__ WT)
{
    __shared__ float ld[64][65];
    const float* srcs[9] = {W2l, g2w1, g2w2, f2w1, f2w2, g1w1, g1w2, f1w2, outw};
    const float* src = srcs[blockIdx.y];
    __hip_bfloat16* dst = WT + (size_t)blockIdx.y * Cc * Cc;
    const int t = threadIdx.x;
    const int k0 = (blockIdx.x >> 2) * 64, n0 = (blockIdx.x & 3) * 64;
#pragma unroll
    for (int j = 0; j < 16; j++) {
        int idx = j * 256 + t; int r = idx >> 6, c = idx & 63;
        ld[r][c] = src[(size_t)(k0 + r) * Cc + n0 + c];
    }
    __syncthreads();
#pragma unroll
    for (int j = 0; j < 16; j++) {
        int idx = j * 256 + t; int n = idx >> 6, k = idx & 63;
        dst[(size_t)(n0 + n) * Cc + k0 + k] = __float2bfloat16(ld[k][n]);
    }
}

// ---------------------------------------------------------------------------
// conv (unchanged from R2)
// ---------------------------------------------------------------------------
__global__ __launch_bounds__(256, 2) void conv_kernel(
    const float* __restrict__ feat, const float* __restrict__ feat_pe,
    const float* __restrict__ Wz, const float* __restrict__ bz,
    __hip_bfloat16* __restrict__ zT, __hip_bfloat16* __restrict__ fT)
{
    extern __shared__ char smem[];
    float (*sS)[36] = (float (*)[36])smem;
    float (*sF)[36] = (float (*)[36])(smem + 256 * 36 * 4);

    const int t = threadIdx.x;
    const int blk = blockIdx.x;
    const int b = blk >> 7;
    const int pix0 = (blk & 127) * 32;

    const float* fp = feat    + ((size_t)(b * Cc + t)) * HW + pix0;
    const float* pp = feat_pe + ((size_t)(b * Cc + t)) * HW + pix0;
#pragma unroll
    for (int j = 0; j < 8; j++) {
        float4 f = *(const float4*)(fp + 4 * j);
        float4 p = *(const float4*)(pp + 4 * j);
        *(float4*)&sF[t][4 * j] = f;
        float4 sm; sm.x = f.x + p.x; sm.y = f.y + p.y; sm.z = f.z + p.z; sm.w = f.w + p.w;
        *(float4*)&sS[t][4 * j] = sm;
    }
    __syncthreads();

    float acc[32];
#pragma unroll
    for (int j = 0; j < 32; j++) acc[j] = 0.f;
    const float* Wc = Wz + t;
    for (int k = 0; k < Cc; k++) {
        float w = Wc[k * Cc];
#pragma unroll
        for (int j = 0; j < 8; j++) {
            float4 a = *(const float4*)&sS[k][4 * j];
            acc[4 * j + 0] = fmaf(a.x, w, acc[4 * j + 0]);
            acc[4 * j + 1] = fmaf(a.y, w, acc[4 * j + 1]);
            acc[4 * j + 2] = fmaf(a.z, w, acc[4 * j + 2]);
            acc[4 * j + 3] = fmaf(a.w, w, acc[4 * j + 3]);
        }
    }
    float bzt = bz[t];
    size_t obase = ((size_t)b * HW + pix0) * Cc + t;
#pragma unroll
    for (int px = 0; px < 32; px++) {
        zT[obase + (size_t)px * Cc] = __float2bfloat16(acc[px] + bzt);
        fT[obase + (size_t)px * Cc] = __float2bfloat16(sF[t][px]);
    }
}

// ---------------------------------------------------------------------------
// MFMA GEMM core, 4-wave (R2 structure): wave w owns cols [w*64, w*64+64),
// all 64 rows.  acc = 16 x f32x4.
// ---------------------------------------------------------------------------
__device__ __forceinline__ void run_gemm(const char* __restrict__ Abuf,
                                         const __bf16* __restrict__ Wt,
                                         const float* __restrict__ bias,
                                         int l15, int lhi, int n0, f32x4* acc)
{
#pragma unroll
    for (int nt = 0; nt < 4; nt++) {
        float bv = bias ? bias[n0 + nt * 16 + l15] : 0.f;
        f32x4 v = {bv, bv, bv, bv};
        acc[0 * 4 + nt] = v; acc[1 * 4 + nt] = v; acc[2 * 4 + nt] = v; acc[3 * 4 + nt] = v;
    }
#pragma unroll
    for (int ks = 0; ks < 8; ks++) {
        bf16x8 bfr[4], afr[4];
#pragma unroll
        for (int nt = 0; nt < 4; nt++)
            bfr[nt] = *(const bf16x8*)(Wt + (size_t)(n0 + nt * 16 + l15) * Cc + ks * 32 + lhi * 8);
#pragma unroll
        for (int mt = 0; mt < 4; mt++) {
            int row = mt * 16 + l15;
            int byte = (row * 512 + (ks * 32 + lhi * 8) * 2) ^ ((row & 7) << 4);
            afr[mt] = *(const bf16x8*)(Abuf + byte);
        }
#pragma unroll
        for (int mt = 0; mt < 4; mt++)
#pragma unroll
            for (int nt = 0; nt < 4; nt++)
                acc[mt * 4 + nt] = __builtin_amdgcn_mfma_f32_16x16x32_bf16(
                    afr[mt], bfr[nt], acc[mt * 4 + nt], 0, 0, 0);
    }
}

// LN stats (R2 structure + defensive entry barrier)
__device__ __forceinline__ void ln_stats(const f32x4* acc, int l15, int lhi, int w, int t,
                                         float* sred, float* smv)
{
    __syncthreads();   // defensive: fence prior GEMM LDS reads vs sred writes
    float s[16], qq[16];
#pragma unroll
    for (int mt = 0; mt < 4; mt++)
#pragma unroll
        for (int i = 0; i < 4; i++) {
            float a = acc[mt * 4 + 0][i], b = acc[mt * 4 + 1][i];
            float c = acc[mt * 4 + 2][i], d = acc[mt * 4 + 3][i];
            s[mt * 4 + i]  = a + b + c + d;
            qq[mt * 4 + i] = a * a + b * b + c * c + d * d;
        }
#pragma unroll
    for (int off = 1; off < 16; off <<= 1)
#pragma unroll
        for (int j = 0; j < 16; j++) {
            s[j]  += __shfl_xor(s[j],  off);
            qq[j] += __shfl_xor(qq[j], off);
        }
    if (l15 == 0) {
#pragma unroll
        for (int mt = 0; mt < 4; mt++)
#pragma unroll
            for (int i = 0; i < 4; i++) {
                int row = mt * 16 + lhi * 4 + i;
                sred[(row * 4 + w) * 2]     = s[mt * 4 + i];
                sred[(row * 4 + w) * 2 + 1] = qq[mt * 4 + i];
            }
    }
    __syncthreads();
    if (t < 64) {
        float ts = sred[(t * 4 + 0) * 2] + sred[(t * 4 + 1) * 2]
                 + sred[(t * 4 + 2) * 2] + sred[(t * 4 + 3) * 2];
        float tq = sred[(t * 4 + 0) * 2 + 1] + sred[(t * 4 + 1) * 2 + 1]
                 + sred[(t * 4 + 2) * 2 + 1] + sred[(t * 4 + 3) * 2 + 1];
        float m = ts * (1.f / 256.f);
        float var = fmaxf(tq * (1.f / 256.f) - m * m, 0.f);
        smv[t * 2]     = m;
        smv[t * 2 + 1] = rsqrtf(var + 1e-5f);
    }
    __syncthreads();
}

__device__ __forceinline__ void gate_apply(const f32x4* acc, const float* __restrict__ g,
                                           const float* __restrict__ bet, const float* smv,
                                           int n0, int l15, int lhi, unsigned* gp)
{
#pragma unroll
    for (int nt = 0; nt < 4; nt++) {
        int col = n0 + nt * 16 + l15;
        float gg = g[col], gb = bet[col];
#pragma unroll
        for (int mt = 0; mt < 4; mt++) {
            float gv[4];
#pragma unroll
            for (int i = 0; i < 4; i++) {
                int row = mt * 16 + lhi * 4 + i;
                float u = (acc[mt * 4 + nt][i] - smv[row * 2]) * smv[row * 2 + 1] * gg + gb;
                gv[i] = 1.f / (1.f + __expf(-u));
            }
            gp[(mt * 4 + nt) * 2]     = pk2(gv[0], gv[1]);
            gp[(mt * 4 + nt) * 2 + 1] = pk2(gv[2], gv[3]);
        }
    }
}

// ---------------------------------------------------------------------------
// fused: R2's proven 4-wave structure (grid 800, block 256, dyn LDS 64KB)
// + batch-per-XCD blockIdx swizzle (pure bijective index remap).
// ---------------------------------------------------------------------------
__global__ __launch_bounds__(256, 2) void fused_kernel(
    const float* __restrict__ bboxes,
    const __hip_bfloat16* __restrict__ qk1, const __hip_bfloat16* __restrict__ qf1,
    const __hip_bfloat16* __restrict__ geW1, const __hip_bfloat16* __restrict__ gef1,
    const __hip_bfloat16* __restrict__ zT, const __hip_bfloat16* __restrict__ fT,
    const __hip_bfloat16* __restrict__ WT,
    const float* __restrict__ b2l,
    const float* __restrict__ g1_b1, const float* __restrict__ g1_b2,
    const float* __restrict__ g1_g,  const float* __restrict__ g1_beta,
    const float* __restrict__ g2_b1, const float* __restrict__ g2_b2,
    const float* __restrict__ g2_g,  const float* __restrict__ g2_beta,
    const float* __restrict__ f1_b2,
    const float* __restrict__ f2_b1, const float* __restrict__ f2_b2,
    const float* __restrict__ out_b, const float* __restrict__ out_g,
    const float* __restrict__ out_beta,
    float* __restrict__ out)
{
    extern __shared__ char smem[];
    char* bufA = smem;            // k buffer   [64][256] bf16 swizzled
    char* bufB = smem + 32768;    // roi/v/intermediates

    __shared__ int   ti[G49][4];
    __shared__ float tw[G49][4];
    __shared__ float sred[64 * 4 * 2];
    __shared__ float smv[64 * 2];

    const int t = threadIdx.x;
    const int lane = t & 63;
    const int w = t >> 6;          // wave id, owns cols [w*64, w*64+64)
    const int n0 = w * 64;
    const int l15 = lane & 15, lhi = lane >> 4;
    // batch-per-XCD swizzle: XCD (bid&7) handles batch (bid&7) only
    const int qid = (blockIdx.x & 7) * NQ + (blockIdx.x >> 3);
    const int b = blockIdx.x & 7;

    const __bf16* WT_W2l  = (const __bf16*)WT + 0 * Cc * Cc;
    const __bf16* WT_g2w1 = (const __bf16*)WT + 1 * Cc * Cc;
    const __bf16* WT_g2w2 = (const __bf16*)WT + 2 * Cc * Cc;
    const __bf16* WT_f2w1 = (const __bf16*)WT + 3 * Cc * Cc;
    const __bf16* WT_f2w2 = (const __bf16*)WT + 4 * Cc * Cc;
    const __bf16* WT_g1w1 = (const __bf16*)WT + 5 * Cc * Cc;
    const __bf16* WT_g1w2 = (const __bf16*)WT + 6 * Cc * Cc;
    const __bf16* WT_f1w2 = (const __bf16*)WT + 7 * Cc * Cc;
    const __bf16* WT_outw = (const __bf16*)WT + 8 * Cc * Cc;

    // --- bilinear tap setup ---
    if (t < G49) {
        float bb0 = bboxes[qid * 4 + 0];
        float bb1 = bboxes[qid * 4 + 1];
        float bb2 = bboxes[qid * 4 + 2];
        float bb3 = bboxes[qid * 4 + 3];
        int s1 = t / 7, s2 = t % 7;
        float ys = bb2 * (1.f / 7.f) * ((float)s1 + 0.5f) + bb1 - 0.5f * bb2;
        float xs = bb3 * (1.f / 7.f) * ((float)s2 + 0.5f) + bb0 - 0.5f * bb3;
        float gx = fminf(fmaxf(2.f * xs - 1.f, -1.f), 1.f);
        float gy = fminf(fmaxf(2.f * ys - 1.f, -1.f), 1.f);
        float ix = ((gx + 1.f) * 64.f - 1.f) * 0.5f;
        float iy = ((gy + 1.f) * 64.f - 1.f) * 0.5f;
        float x0f = floorf(ix), y0f = floorf(iy);
        float wx1 = ix - x0f, wx0 = 1.f - wx1;
        float wy1 = iy - y0f, wy0 = 1.f - wy1;
        int x0 = (int)x0f, y0 = (int)y0f;
        int x1 = x0 + 1, y1 = y0 + 1;
        bool vx0 = (x0 >= 0) & (x0 < 64), vx1 = (x1 >= 0) & (x1 < 64);
        bool vy0 = (y0 >= 0) & (y0 < 64), vy1 = (y1 >= 0) & (y1 < 64);
        int cx0 = min(max(x0, 0), 63), cx1 = min(max(x1, 0), 63);
        int cy0 = min(max(y0, 0), 63), cy1 = min(max(y1, 0), 63);
        ti[t][0] = cy0 * 64 + cx0; tw[t][0] = (vx0 && vy0) ? wx0 * wy0 : 0.f;
        ti[t][1] = cy0 * 64 + cx1; tw[t][1] = (vx1 && vy0) ? wx1 * wy0 : 0.f;
        ti[t][2] = cy1 * 64 + cx0; tw[t][2] = (vx0 && vy1) ? wx0 * wy1 : 0.f;
        ti[t][3] = cy1 * 64 + cx1; tw[t][3] = (vx1 && vy1) ? wx1 * wy1 : 0.f;
    }
    // zero pad rows of bufB once
    for (int r = G49; r < 64; r++) lwb16(bufB, r, t, 0.f);
    __syncthreads();

    // --- sample roi (from z) -> bufB ---
    {
        const __hip_bfloat16* zb = zT + (size_t)b * HW * Cc;
        for (int r = 0; r < G49; r++) {
            float az = 0.f;
#pragma unroll
            for (int p = 0; p < 4; p++) {
                float wt_ = tw[r][p];
                if (wt_ != 0.f) az += wt_ * ldbf(&zb[(size_t)ti[r][p] * Cc + t]);
            }
            lwb16(bufB, r, t, az);
        }
    }
    __syncthreads();

    f32x4 acc[16];

    // --- G1: roi @ W2l + b2l ; k = (qk1+geW1)*acc -> bufA ---
    run_gemm(bufB, WT_W2l, b2l, l15, lhi, n0, acc);
    __syncthreads();   // defensive: fence bufB reads before bufA writes
#pragma unroll
    for (int nt = 0; nt < 4; nt++) {
        int col = n0 + nt * 16 + l15;
        float qk = ldbf(&qk1[qid * Cc + col]);
#pragma unroll
        for (int mt = 0; mt < 4; mt++)
#pragma unroll
            for (int i = 0; i < 4; i++) {
                int row = mt * 16 + lhi * 4 + i;
                float gw = (row < G49) ? ldbf(&geW1[row * Cc + col]) : 0.f;
                lwb16(bufA, row, col, (qk + gw) * acc[mt * 4 + nt][i]);
            }
    }
    __syncthreads();

    // --- G4: k @ g2_w1 -> relu -> bufB ---
    run_gemm(bufA, WT_g2w1, g2_b1, l15, lhi, n0, acc);
    __syncthreads();
#pragma unroll
    for (int nt = 0; nt < 4; nt++)
#pragma unroll
        for (int mt = 0; mt < 4; mt++)
#pragma unroll
            for (int i = 0; i < 4; i++)
                lwb16(bufB, mt * 16 + lhi * 4 + i, n0 + nt * 16 + l15,
                      fmaxf(acc[mt * 4 + nt][i], 0.f));
    __syncthreads();

    // --- G5: @ g2_w2 ; LN ; gate2 ---
    run_gemm(bufB, WT_g2w2, g2_b2, l15, lhi, n0, acc);
    ln_stats(acc, l15, lhi, w, t, sred, smv);
    unsigned g2p[32];
    gate_apply(acc, g2_g, g2_beta, smv, n0, l15, lhi, g2p);

    // --- sample v (from feat) -> bufB --- (bufB readers fenced inside ln_stats)
    {
        const __hip_bfloat16* fb = fT + (size_t)b * HW * Cc;
        for (int r = 0; r < G49; r++) {
            float av = 0.f;
#pragma unroll
            for (int p = 0; p < 4; p++) {
                float wt_ = tw[r][p];
                if (wt_ != 0.f) av += wt_ * ldbf(&fb[(size_t)ti[r][p] * Cc + t]);
            }
            lwb16(bufB, r, t, av);
        }
    }
    __syncthreads();

    // --- G2: v @ f2_w1 -> relu -> bufB (in place) ---
    run_gemm(bufB, WT_f2w1, f2_b1, l15, lhi, n0, acc);
    __syncthreads();
#pragma unroll
    for (int nt = 0; nt < 4; nt++)
#pragma unroll
        for (int mt = 0; mt < 4; mt++)
#pragma unroll
            for (int i = 0; i < 4; i++)
                lwb16(bufB, mt * 16 + lhi * 4 + i, n0 + nt * 16 + l15,
                      fmaxf(acc[mt * 4 + nt][i], 0.f));
    __syncthreads();

    // --- G3: @ f2_w2 ; comb = gate2 * m2 (packed regs) ---
    run_gemm(bufB, WT_f2w2, f2_b2, l15, lhi, n0, acc);
    __syncthreads();
    unsigned comb[32];
#pragma unroll
    for (int j = 0; j < 16; j++) {
        comb[j * 2]     = pk2(upk(g2p[j * 2], 0) * acc[j][0], upk(g2p[j * 2], 1) * acc[j][1]);
        comb[j * 2 + 1] = pk2(upk(g2p[j * 2 + 1], 0) * acc[j][2], upk(g2p[j * 2 + 1], 1) * acc[j][3]);
    }

    // --- G7: k @ g1_w1 -> relu -> bufB ---
    run_gemm(bufA, WT_g1w1, g1_b1, l15, lhi, n0, acc);
    __syncthreads();   // defensive: fence bufA reads before bufB writes
#pragma unroll
    for (int nt = 0; nt < 4; nt++)
#pragma unroll
        for (int mt = 0; mt < 4; mt++)
#pragma unroll
            for (int i = 0; i < 4; i++)
                lwb16(bufB, mt * 16 + lhi * 4 + i, n0 + nt * 16 + l15,
                      fmaxf(acc[mt * 4 + nt][i], 0.f));
    __syncthreads();

    // --- G8: @ g1_w2 ; LN ; gate1 ---
    run_gemm(bufB, WT_g1w2, g1_b2, l15, lhi, n0, acc);
    ln_stats(acc, l15, lhi, w, t, sred, smv);
    unsigned g1p[32];
    gate_apply(acc, g1_g, g1_beta, smv, n0, l15, lhi, g1p);

    // --- m1 layer1 (no GEMM): relu(qf1[col] + gef1[row][col]) -> bufB ---
    {
        float qf = ldbf(&qf1[qid * Cc + t]);
        for (int r = 0; r < 64; r++) {
            int rr = r < G49 ? r : 0;
            lwb16(bufB, r, t, fmaxf(qf + ldbf(&gef1[rr * Cc + t]), 0.f));
        }
    }
    __syncthreads();

    // --- G6: @ f1_w2 ; final = comb + gate1*m1 -> bufB (in place) ---
    run_gemm(bufB, WT_f1w2, f1_b2, l15, lhi, n0, acc);
    __syncthreads();
#pragma unroll
    for (int nt = 0; nt < 4; nt++)
#pragma unroll
        for (int mt = 0; mt < 4; mt++)
#pragma unroll
            for (int i = 0; i < 4; i++) {
                int j = mt * 4 + nt;
                int hw_ = i >> 1, lo = i & 1;
                float f = upk(comb[j * 2 + hw_], lo) + upk(g1p[j * 2 + hw_], lo) * acc[j][i];
                lwb16(bufB, mt * 16 + lhi * 4 + i, n0 + nt * 16 + l15, f);
            }
    __syncthreads();

    // --- G9: @ out_w ; LN ; store ---
    run_gemm(bufB, WT_outw, out_b, l15, lhi, n0, acc);
    ln_stats(acc, l15, lhi, w, t, sred, smv);
#pragma unroll
    for (int nt = 0; nt < 4; nt++) {
        int col = n0 + nt * 16 + l15;
        float gg = out_g[col], gb = out_beta[col];
#pragma unroll
        for (int mt = 0; mt < 4; mt++)
#pragma unroll
            for (int i = 0; i < 4; i++) {
                int row = mt * 16 + lhi * 4 + i;
                if (row < G49)
                    out[((size_t)qid * G49 + row) * Cc + col] =
                        (acc[mt * 4 + nt][i] - smv[row * 2]) * smv[row * 2 + 1] * gg + gb;
            }
    }
}

// ---------------------------------------------------------------------------
extern "C" void kernel_launch(void* const* d_in, const int* in_sizes, int n_in,
                              void* d_out, int out_size, void* d_ws, size_t ws_size,
                              hipStream_t stream)
{
    const float* q       = (const float*)d_in[0];
    const float* qpe     = (const float*)d_in[1];
    const float* feat    = (const float*)d_in[2];
    const float* feat_pe = (const float*)d_in[3];
    const float* bboxes  = (const float*)d_in[4];
    const float* ge      = (const float*)d_in[5];
    const float* Wz      = (const float*)d_in[6];
    const float* Wq      = (const float*)d_in[7];
    const float* W1l     = (const float*)d_in[8];
    const float* W2l     = (const float*)d_in[9];
    const float* g1_w1   = (const float*)d_in[10];
    const float* g1_w2   = (const float*)d_in[11];
    const float* g2_w1   = (const float*)d_in[12];
    const float* g2_w2   = (const float*)d_in[13];
    const float* f1_w1   = (const float*)d_in[14];
    const float* f1_w2   = (const float*)d_in[15];
    const float* f2_w1   = (const float*)d_in[16];
    const float* f2_w2   = (const float*)d_in[17];
    const float* out_w   = (const float*)d_in[18];
    const float* bz      = (const float*)d_in[19];
    const float* bq      = (const float*)d_in[20];
    const float* b1l     = (const float*)d_in[21];
    const float* b2l     = (const float*)d_in[22];
    const float* g1_b1   = (const float*)d_in[23];
    const float* g1_b2   = (const float*)d_in[24];
    const float* g2_b1   = (const float*)d_in[25];
    const float* g2_b2   = (const float*)d_in[26];
    const float* f1_b1   = (const float*)d_in[27];
    const float* f1_b2   = (const float*)d_in[28];
    const float* f2_b1   = (const float*)d_in[29];
    const float* f2_b2   = (const float*)d_in[30];
    const float* out_b   = (const float*)d_in[31];
    const float* g1_beta = (const float*)d_in[32];
    const float* g2_beta = (const float*)d_in[33];
    const float* out_beta= (const float*)d_in[34];
    const float* g1_g    = (const float*)d_in[35];
    const float* g2_g    = (const float*)d_in[36];
    const float* out_g   = (const float*)d_in[37];

    char* ws = (char*)d_ws;
    __hip_bfloat16* qk1  = (__hip_bfloat16*)(ws);                 // 409600
    __hip_bfloat16* qf1  = (__hip_bfloat16*)(ws + 409600);        // 409600
    __hip_bfloat16* geW1 = (__hip_bfloat16*)(ws + 819200);        // 25088
    __hip_bfloat16* gef1 = (__hip_bfloat16*)(ws + 844288);        // 25088
    __hip_bfloat16* WT   = (__hip_bfloat16*)(ws + 869376);        // 1179648
    __hip_bfloat16* zT   = (__hip_bfloat16*)(ws + 2049024);       // 16777216
    __hip_bfloat16* fT   = (__hip_bfloat16*)(ws + 18826240);      // 16777216

    prep1_kernel<<<dim3(Bb * NQ + G49), dim3(256), 0, stream>>>(
        q, qpe, ge, Wq, bq, W1l, b1l, f1_w1, f1_b1, qk1, qf1, geW1, gef1);

    wprep_kernel<<<dim3(16, 9), dim3(256), 0, stream>>>(
        W2l, g2_w1, g2_w2, f2_w1, f2_w2, g1_w1, g1_w2, f1_w2, out_w, WT);

    conv_kernel<<<dim3(1024), dim3(256), 2 * 256 * 36 * 4, stream>>>(
        feat, feat_pe, Wz, bz, zT, fT);

    fused_kernel<<<dim3(Bb * NQ), dim3(256), 65536, stream>>>(
        bboxes, qk1, qf1, geW1, gef1, zT, fT, WT,
        b2l,
        g1_b1, g1_b2, g1_g, g1_beta,
        g2_b1, g2_b2, g2_g, g2_beta,
        f1_b2, f2_b1, f2_b2,
        out_b, out_g, out_beta, (float*)d_out);
}

// Round 6
// 464.367 us; speedup vs baseline: 7.5743x; 1.4812x over previous
//
#include <hip/hip_runtime.h>
#include <hip/hip_bf16.h>

constexpr int Cc  = 256;
constexpr int NQ  = 100;
constexpr int Bb  = 8;
constexpr int HW  = 64 * 64;
constexpr int G49 = 49;

typedef __bf16 bf16x8 __attribute__((ext_vector_type(8)));
typedef float  f32x4  __attribute__((ext_vector_type(4)));

__device__ __forceinline__ float ldbf(const __hip_bfloat16* p) { return __bfloat162float(*p); }

__device__ __forceinline__ unsigned pk2(float a, float b) {
    union { unsigned u; __bf16 h[2]; } x;
    x.h[0] = (__bf16)a; x.h[1] = (__bf16)b;
    return x.u;
}
__device__ __forceinline__ float upk(unsigned u, int k) {
    union { unsigned u2; __bf16 h[2]; } x; x.u2 = u;
    return (float)x.h[k];
}

// swizzled bf16 LDS write: buffer [64 rows][256 cols] bf16, row stride 512B,
// byte ^= (row&7)<<4 (T2 swizzle)
__device__ __forceinline__ void lwb16(char* buf, int row, int col, float v) {
    int byte = (row * 512 + col * 2) ^ ((row & 7) << 4);
    *(__bf16*)(buf + byte) = (__bf16)v;
}

// ---------------------------------------------------------------------------
// prep1 (unchanged from R5)
// ---------------------------------------------------------------------------
__global__ void prep1_kernel(const float* __restrict__ q, const float* __restrict__ qpe,
                             const float* __restrict__ ge,
                             const float* __restrict__ Wq, const float* __restrict__ bq,
                             const float* __restrict__ W1l, const float* __restrict__ b1l,
                             const float* __restrict__ f1_w1, const float* __restrict__ f1_b1,
                             __hip_bfloat16* __restrict__ qk1, __hip_bfloat16* __restrict__ qf1,
                             __hip_bfloat16* __restrict__ geW1, __hip_bfloat16* __restrict__ gef1)
{
    __shared__ float s[Cc];
    __shared__ float rq[Cc];
    __shared__ float qqs[Cc];
    const int t = threadIdx.x;
    const int blk = blockIdx.x;
    if (blk < Bb * NQ) {
        float a = q[blk * Cc + t], p = qpe[blk * Cc + t];
        rq[t] = a; s[t] = a + p;
        __syncthreads();
        float acc1 = bq[t], acc2 = f1_b1[t];
        for (int k = 0; k < Cc; k++) {
            acc1 = fmaf(s[k],  Wq[k * Cc + t],    acc1);
            acc2 = fmaf(rq[k], f1_w1[k * Cc + t], acc2);
        }
        qqs[t] = acc1;
        qf1[blk * Cc + t] = __float2bfloat16(acc2);
        __syncthreads();
        float acc3 = b1l[t];
        for (int k = 0; k < Cc; k++) acc3 = fmaf(qqs[k], W1l[k * Cc + t], acc3);
        qk1[blk * Cc + t] = __float2bfloat16(acc3);
    } else {
        int g = blk - Bb * NQ;
        s[t] = ge[g * Cc + t];
        __syncthreads();
        float acc1 = 0.f, acc2 = 0.f;
        for (int k = 0; k < Cc; k++) {
            acc1 = fmaf(s[k], W1l[k * Cc + t],   acc1);
            acc2 = fmaf(s[k], f1_w1[k * Cc + t], acc2);
        }
        geW1[g * Cc + t] = __float2bfloat16(acc1);
        gef1[g * Cc + t] = __float2bfloat16(acc2);
    }
}

// ---------------------------------------------------------------------------
// wprep: W[k][n] f32 -> fragment-ordered bf16 WTf[m][w][nt][ks][lane][8]
//   entry = W[k][n], n = w*64+nt*16+(l&15), k = ks*32+(l>>4)*8+e
// One B-frag load in fused = contiguous 1KB (64 lanes x 16B), fully coalesced.
// grid (4 k-chunks, 4 w, 10 m), block 256
// ---------------------------------------------------------------------------
__global__ void wprep_kernel(const float* __restrict__ Wz,  const float* __restrict__ W2l,
                             const float* __restrict__ g2w1, const float* __restrict__ g2w2,
                             const float* __restrict__ f2w1, const float* __restrict__ f2w2,
                             const float* __restrict__ g1w1, const float* __restrict__ g1w2,
                             const float* __restrict__ f1w2, const float* __restrict__ outw,
                             __hip_bfloat16* __restrict__ WTf)
{
    __shared__ float ld[64][65];
    const float* srcs[10] = {Wz, W2l, g2w1, g2w2, f2w1, f2w2, g1w1, g1w2, f1w2, outw};
    const int m  = blockIdx.z;
    const int w  = blockIdx.y;            // n0 = w*64
    const int k0 = blockIdx.x * 64;
    const float* src = srcs[m];
    __hip_bfloat16* dst = WTf + (size_t)m * 65536;
    const int t = threadIdx.x;
    const int n0 = w * 64;
#pragma unroll
    for (int j = 0; j < 16; j++) {
        int idx = j * 256 + t; int r = idx >> 6, c = idx & 63;
        ld[r][c] = src[(size_t)(k0 + r) * Cc + n0 + c];
    }
    __syncthreads();
#pragma unroll
    for (int j = 0; j < 16; j++) {
        int idx = j * 256 + t;                 // [0,4096)
        int e  = idx & 7;
        int l  = (idx >> 3) & 63;
        int kk = (idx >> 9) & 1;
        int nt = idx >> 10;
        int k_loc = kk * 32 + ((l >> 4) & 3) * 8 + e;
        int n_loc = nt * 16 + (l & 15);
        int oofs  = ((w * 4 + nt) * 8 + (k0 >> 5) + kk) * 512 + (idx & 511);
        dst[oofs] = __float2bfloat16(ld[k_loc][n_loc]);
    }
}

// ---------------------------------------------------------------------------
// tr: transpose feat/feat_pe [B,C,HW] f32 -> fT/pT [B,HW,C] bf16
// grid 1024 (8 batches x 128 pixel-chunks of 32), block 256 (thread = channel)
// ---------------------------------------------------------------------------
__global__ void tr_kernel(const float* __restrict__ feat, const float* __restrict__ feat_pe,
                          __hip_bfloat16* __restrict__ fT, __hip_bfloat16* __restrict__ pT)
{
    const int t = threadIdx.x;
    const int blk = blockIdx.x;
    const int b = blk >> 7;
    const int pix0 = (blk & 127) * 32;
    const float* fp = feat    + ((size_t)(b * Cc + t)) * HW + pix0;
    const float* pp = feat_pe + ((size_t)(b * Cc + t)) * HW + pix0;
    size_t obase = ((size_t)b * HW + pix0) * Cc + t;
#pragma unroll
    for (int j = 0; j < 8; j++) {
        float4 f = *(const float4*)(fp + 4 * j);
        float4 p = *(const float4*)(pp + 4 * j);
        fT[obase + (size_t)(4 * j + 0) * Cc] = __float2bfloat16(f.x);
        fT[obase + (size_t)(4 * j + 1) * Cc] = __float2bfloat16(f.y);
        fT[obase + (size_t)(4 * j + 2) * Cc] = __float2bfloat16(f.z);
        fT[obase + (size_t)(4 * j + 3) * Cc] = __float2bfloat16(f.w);
        pT[obase + (size_t)(4 * j + 0) * Cc] = __float2bfloat16(p.x);
        pT[obase + (size_t)(4 * j + 1) * Cc] = __float2bfloat16(p.y);
        pT[obase + (size_t)(4 * j + 2) * Cc] = __float2bfloat16(p.z);
        pT[obase + (size_t)(4 * j + 3) * Cc] = __float2bfloat16(p.w);
    }
}

// ---------------------------------------------------------------------------
// MFMA GEMM core (4-wave, frag-ordered weights): wave w owns cols [w*64,+64).
// B-frag load = contiguous 1KB per wave instruction.
// ---------------------------------------------------------------------------
__device__ __forceinline__ void run_gemm(const char* __restrict__ Abuf,
                                         const __bf16* __restrict__ Wf,
                                         const float* __restrict__ bias,
                                         int l15, int lhi, int lane, int w, int n0, f32x4* acc)
{
#pragma unroll
    for (int nt = 0; nt < 4; nt++) {
        float bv = bias ? bias[n0 + nt * 16 + l15] : 0.f;
        f32x4 v = {bv, bv, bv, bv};
        acc[0 * 4 + nt] = v; acc[1 * 4 + nt] = v; acc[2 * 4 + nt] = v; acc[3 * 4 + nt] = v;
    }
#pragma unroll
    for (int ks = 0; ks < 8; ks++) {
        bf16x8 bfr[4], afr[4];
#pragma unroll
        for (int nt = 0; nt < 4; nt++)
            bfr[nt] = *(const bf16x8*)(Wf + ((((w * 4 + nt) * 8 + ks) * 64) + lane) * 8);
#pragma unroll
        for (int mt = 0; mt < 4; mt++) {
            int row = mt * 16 + l15;
            int byte = (row * 512 + (ks * 32 + lhi * 8) * 2) ^ ((row & 7) << 4);
            afr[mt] = *(const bf16x8*)(Abuf + byte);
        }
#pragma unroll
        for (int mt = 0; mt < 4; mt++)
#pragma unroll
            for (int nt = 0; nt < 4; nt++)
                acc[mt * 4 + nt] = __builtin_amdgcn_mfma_f32_16x16x32_bf16(
                    afr[mt], bfr[nt], acc[mt * 4 + nt], 0, 0, 0);
    }
}

// LN stats (entry barrier: fences prior GEMM LDS reads)
__device__ __forceinline__ void ln_stats(const f32x4* acc, int l15, int lhi, int w, int t,
                                         float* sred, float* smv)
{
    __syncthreads();
    float s[16], qq[16];
#pragma unroll
    for (int mt = 0; mt < 4; mt++)
#pragma unroll
        for (int i = 0; i < 4; i++) {
            float a = acc[mt * 4 + 0][i], b = acc[mt * 4 + 1][i];
            float c = acc[mt * 4 + 2][i], d = acc[mt * 4 + 3][i];
            s[mt * 4 + i]  = a + b + c + d;
            qq[mt * 4 + i] = a * a + b * b + c * c + d * d;
        }
#pragma unroll
    for (int off = 1; off < 16; off <<= 1)
#pragma unroll
        for (int j = 0; j < 16; j++) {
            s[j]  += __shfl_xor(s[j],  off);
            qq[j] += __shfl_xor(qq[j], off);
        }
    if (l15 == 0) {
#pragma unroll
        for (int mt = 0; mt < 4; mt++)
#pragma unroll
            for (int i = 0; i < 4; i++) {
                int row = mt * 16 + lhi * 4 + i;
                sred[(row * 4 + w) * 2]     = s[mt * 4 + i];
                sred[(row * 4 + w) * 2 + 1] = qq[mt * 4 + i];
            }
    }
    __syncthreads();
    if (t < 64) {
        float ts = sred[(t * 4 + 0) * 2] + sred[(t * 4 + 1) * 2]
                 + sred[(t * 4 + 2) * 2] + sred[(t * 4 + 3) * 2];
        float tq = sred[(t * 4 + 0) * 2 + 1] + sred[(t * 4 + 1) * 2 + 1]
                 + sred[(t * 4 + 2) * 2 + 1] + sred[(t * 4 + 3) * 2 + 1];
        float m = ts * (1.f / 256.f);
        float var = fmaxf(tq * (1.f / 256.f) - m * m, 0.f);
        smv[t * 2]     = m;
        smv[t * 2 + 1] = rsqrtf(var + 1e-5f);
    }
    __syncthreads();
}

__device__ __forceinline__ void gate_apply(const f32x4* acc, const float* __restrict__ g,
                                           const float* __restrict__ bet, const float* smv,
                                           int n0, int l15, int lhi, unsigned* gp)
{
#pragma unroll
    for (int nt = 0; nt < 4; nt++) {
        int col = n0 + nt * 16 + l15;
        float gg = g[col], gb = bet[col];
#pragma unroll
        for (int mt = 0; mt < 4; mt++) {
            float gv[4];
#pragma unroll
            for (int i = 0; i < 4; i++) {
                int row = mt * 16 + lhi * 4 + i;
                float u = (acc[mt * 4 + nt][i] - smv[row * 2]) * smv[row * 2 + 1] * gg + gb;
                gv[i] = 1.f / (1.f + __expf(-u));
            }
            gp[(mt * 4 + nt) * 2]     = pk2(gv[0], gv[1]);
            gp[(mt * 4 + nt) * 2 + 1] = pk2(gv[2], gv[3]);
        }
    }
}

// ---------------------------------------------------------------------------
// fused: 4-wave structure (grid 800, block 256, dyn LDS 64KB), XCD swizzle.
// z eliminated: roi = (sample(feat)+sample(feat_pe)) @ Wz + bz   (G0).
// k persists in bufB; transients ping through bufA (in-place after barrier).
// ---------------------------------------------------------------------------
__global__ __launch_bounds__(256, 2) void fused_kernel(
    const float* __restrict__ bboxes,
    const __hip_bfloat16* __restrict__ qk1, const __hip_bfloat16* __restrict__ qf1,
    const __hip_bfloat16* __restrict__ geW1, const __hip_bfloat16* __restrict__ gef1,
    const __hip_bfloat16* __restrict__ fT, const __hip_bfloat16* __restrict__ pT,
    const __hip_bfloat16* __restrict__ WTf,
    const float* __restrict__ bz,    const float* __restrict__ b2l,
    const float* __restrict__ g1_b1, const float* __restrict__ g1_b2,
    const float* __restrict__ g1_g,  const float* __restrict__ g1_beta,
    const float* __restrict__ g2_b1, const float* __restrict__ g2_b2,
    const float* __restrict__ g2_g,  const float* __restrict__ g2_beta,
    const float* __restrict__ f1_b2,
    const float* __restrict__ f2_b1, const float* __restrict__ f2_b2,
    const float* __restrict__ out_b, const float* __restrict__ out_g,
    const float* __restrict__ out_beta,
    float* __restrict__ out)
{
    extern __shared__ char smem[];
    char* bufA = smem;            // transient A operands
    char* bufB = smem + 32768;    // vp -> roi -> k (persistent)

    __shared__ int   ti[G49][4];
    __shared__ float tw[G49][4];
    __shared__ float sred[64 * 4 * 2];
    __shared__ float smv[64 * 2];

    const int t = threadIdx.x;
    const int lane = t & 63;
    const int w = t >> 6;
    const int n0 = w * 64;
    const int l15 = lane & 15, lhi = lane >> 4;
    const int qid = (blockIdx.x & 7) * NQ + (blockIdx.x >> 3);
    const int b = blockIdx.x & 7;

    const __bf16* Wf_z    = (const __bf16*)WTf + 0 * 65536;
    const __bf16* Wf_W2l  = (const __bf16*)WTf + 1 * 65536;
    const __bf16* Wf_g2w1 = (const __bf16*)WTf + 2 * 65536;
    const __bf16* Wf_g2w2 = (const __bf16*)WTf + 3 * 65536;
    const __bf16* Wf_f2w1 = (const __bf16*)WTf + 4 * 65536;
    const __bf16* Wf_f2w2 = (const __bf16*)WTf + 5 * 65536;
    const __bf16* Wf_g1w1 = (const __bf16*)WTf + 6 * 65536;
    const __bf16* Wf_g1w2 = (const __bf16*)WTf + 7 * 65536;
    const __bf16* Wf_f1w2 = (const __bf16*)WTf + 8 * 65536;
    const __bf16* Wf_outw = (const __bf16*)WTf + 9 * 65536;

    // --- bilinear tap setup ---
    if (t < G49) {
        float bb0 = bboxes[qid * 4 + 0];
        float bb1 = bboxes[qid * 4 + 1];
        float bb2 = bboxes[qid * 4 + 2];
        float bb3 = bboxes[qid * 4 + 3];
        int s1 = t / 7, s2 = t % 7;
        float ys = bb2 * (1.f / 7.f) * ((float)s1 + 0.5f) + bb1 - 0.5f * bb2;
        float xs = bb3 * (1.f / 7.f) * ((float)s2 + 0.5f) + bb0 - 0.5f * bb3;
        float gx = fminf(fmaxf(2.f * xs - 1.f, -1.f), 1.f);
        float gy = fminf(fmaxf(2.f * ys - 1.f, -1.f), 1.f);
        float ix = ((gx + 1.f) * 64.f - 1.f) * 0.5f;
        float iy = ((gy + 1.f) * 64.f - 1.f) * 0.5f;
        float x0f = floorf(ix), y0f = floorf(iy);
        float wx1 = ix - x0f, wx0 = 1.f - wx1;
        float wy1 = iy - y0f, wy0 = 1.f - wy1;
        int x0 = (int)x0f, y0 = (int)y0f;
        int x1 = x0 + 1, y1 = y0 + 1;
        bool vx0 = (x0 >= 0) & (x0 < 64), vx1 = (x1 >= 0) & (x1 < 64);
        bool vy0 = (y0 >= 0) & (y0 < 64), vy1 = (y1 >= 0) & (y1 < 64);
        int cx0 = min(max(x0, 0), 63), cx1 = min(max(x1, 0), 63);
        int cy0 = min(max(y0, 0), 63), cy1 = min(max(y1, 0), 63);
        ti[t][0] = cy0 * 64 + cx0; tw[t][0] = (vx0 && vy0) ? wx0 * wy0 : 0.f;
        ti[t][1] = cy0 * 64 + cx1; tw[t][1] = (vx1 && vy0) ? wx1 * wy0 : 0.f;
        ti[t][2] = cy1 * 64 + cx0; tw[t][2] = (vx0 && vy1) ? wx0 * wy1 : 0.f;
        ti[t][3] = cy1 * 64 + cx1; tw[t][3] = (vx1 && vy1) ? wx1 * wy1 : 0.f;
    }
    // zero pad rows of both buffers
    for (int r = G49; r < 64; r++) { lwb16(bufA, r, t, 0.f); lwb16(bufB, r, t, 0.f); }
    __syncthreads();

    // --- S: sample v (feat) -> bufA ; vp = v + sample(feat_pe) -> bufB ---
    {
        const __hip_bfloat16* fb = fT + (size_t)b * HW * Cc;
        const __hip_bfloat16* pb = pT + (size_t)b * HW * Cc;
        for (int r = 0; r < G49; r++) {
            float av = 0.f, ap = 0.f;
#pragma unroll
            for (int p = 0; p < 4; p++) {
                float wt_ = tw[r][p];
                if (wt_ != 0.f) {
                    size_t o = (size_t)ti[r][p] * Cc + t;
                    av += wt_ * ldbf(&fb[o]);
                    ap += wt_ * ldbf(&pb[o]);
                }
            }
            lwb16(bufA, r, t, av);
            lwb16(bufB, r, t, av + ap);
        }
    }
    __syncthreads();

    f32x4 acc[16];

    // --- G0: roi = vp @ Wz + bz -> bufB (in place) ---
    run_gemm(bufB, Wf_z, bz, l15, lhi, lane, w, n0, acc);
    __syncthreads();
#pragma unroll
    for (int nt = 0; nt < 4; nt++)
#pragma unroll
        for (int mt = 0; mt < 4; mt++)
#pragma unroll
            for (int i = 0; i < 4; i++)
                lwb16(bufB, mt * 16 + lhi * 4 + i, n0 + nt * 16 + l15, acc[mt * 4 + nt][i]);
    __syncthreads();

    // --- G1: k = (qk1+geW1) * (roi @ W2l + b2l) -> bufB (in place, persistent) ---
    run_gemm(bufB, Wf_W2l, b2l, l15, lhi, lane, w, n0, acc);
    __syncthreads();
#pragma unroll
    for (int nt = 0; nt < 4; nt++) {
        int col = n0 + nt * 16 + l15;
        float qk = ldbf(&qk1[qid * Cc + col]);
#pragma unroll
        for (int mt = 0; mt < 4; mt++)
#pragma unroll
            for (int i = 0; i < 4; i++) {
                int row = mt * 16 + lhi * 4 + i;
                float gw = (row < G49) ? ldbf(&geW1[row * Cc + col]) : 0.f;
                lwb16(bufB, row, col, (qk + gw) * acc[mt * 4 + nt][i]);
            }
    }
    __syncthreads();

    // --- G2: v @ f2_w1 -> relu -> bufA (in place) ---
    run_gemm(bufA, Wf_f2w1, f2_b1, l15, lhi, lane, w, n0, acc);
    __syncthreads();
#pragma unroll
    for (int nt = 0; nt < 4; nt++)
#pragma unroll
        for (int mt = 0; mt < 4; mt++)
#pragma unroll
            for (int i = 0; i < 4; i++)
                lwb16(bufA, mt * 16 + lhi * 4 + i, n0 + nt * 16 + l15,
                      fmaxf(acc[mt * 4 + nt][i], 0.f));
    __syncthreads();

    // --- G3: m2 = bufA @ f2_w2 + f2_b2 (held packed in regs) ---
    run_gemm(bufA, Wf_f2w2, f2_b2, l15, lhi, lane, w, n0, acc);
    unsigned m2p[32];
#pragma unroll
    for (int j = 0; j < 16; j++) {
        m2p[j * 2]     = pk2(acc[j][0], acc[j][1]);
        m2p[j * 2 + 1] = pk2(acc[j][2], acc[j][3]);
    }
    // (no barrier: G4 reads bufB only; its post-gemm barrier fences bufA reads)

    // --- G4: k @ g2_w1 -> relu -> bufA ---
    run_gemm(bufB, Wf_g2w1, g2_b1, l15, lhi, lane, w, n0, acc);
    __syncthreads();
#pragma unroll
    for (int nt = 0; nt < 4; nt++)
#pragma unroll
        for (int mt = 0; mt < 4; mt++)
#pragma unroll
            for (int i = 0; i < 4; i++)
                lwb16(bufA, mt * 16 + lhi * 4 + i, n0 + nt * 16 + l15,
                      fmaxf(acc[mt * 4 + nt][i], 0.f));
    __syncthreads();

    // --- G5: @ g2_w2 ; LN ; gate2 ; comb = gate2*m2 ---
    run_gemm(bufA, Wf_g2w2, g2_b2, l15, lhi, lane, w, n0, acc);
    ln_stats(acc, l15, lhi, w, t, sred, smv);
    unsigned g2p[32];
    gate_apply(acc, g2_g, g2_beta, smv, n0, l15, lhi, g2p);
    unsigned comb[32];
#pragma unroll
    for (int j = 0; j < 32; j++)
        comb[j] = pk2(upk(g2p[j], 0) * upk(m2p[j], 0), upk(g2p[j], 1) * upk(m2p[j], 1));

    // --- G7: k @ g1_w1 -> relu -> bufA ---  (G5's bufA reads fenced in ln_stats)
    run_gemm(bufB, Wf_g1w1, g1_b1, l15, lhi, lane, w, n0, acc);
    __syncthreads();
#pragma unroll
    for (int nt = 0; nt < 4; nt++)
#pragma unroll
        for (int mt = 0; mt < 4; mt++)
#pragma unroll
            for (int i = 0; i < 4; i++)
                lwb16(bufA, mt * 16 + lhi * 4 + i, n0 + nt * 16 + l15,
                      fmaxf(acc[mt * 4 + nt][i], 0.f));
    __syncthreads();

    // --- G8: @ g1_w2 ; LN ; gate1 ---
    run_gemm(bufA, Wf_g1w2, g1_b2, l15, lhi, lane, w, n0, acc);
    ln_stats(acc, l15, lhi, w, t, sred, smv);
    unsigned g1p[32];
    gate_apply(acc, g1_g, g1_beta, smv, n0, l15, lhi, g1p);

    // --- m1 layer1: relu(qf1[col] + gef1[row][col]) -> bufA ---
    {
        float qf = ldbf(&qf1[qid * Cc + t]);
        for (int r = 0; r < 64; r++) {
            int rr = r < G49 ? r : 0;
            lwb16(bufA, r, t, fmaxf(qf + ldbf(&gef1[rr * Cc + t]), 0.f));
        }
    }
    __syncthreads();

    // --- G6: @ f1_w2 ; final = comb + gate1*m1 -> bufA (in place) ---
    run_gemm(bufA, Wf_f1w2, f1_b2, l15, lhi, lane, w, n0, acc);
    __syncthreads();
#pragma unroll
    for (int nt = 0; nt < 4; nt++)
#pragma unroll
        for (int mt = 0; mt < 4; mt++)
#pragma unroll
            for (int i = 0; i < 4; i++) {
                int j = mt * 4 + nt;
                int hw_ = i >> 1, lo = i & 1;
                float f = upk(comb[j * 2 + hw_], lo) + upk(g1p[j * 2 + hw_], lo) * acc[j][i];
                lwb16(bufA, mt * 16 + lhi * 4 + i, n0 + nt * 16 + l15, f);
            }
    __syncthreads();

    // --- G9: @ out_w ; LN ; store ---
    run_gemm(bufA, Wf_outw, out_b, l15, lhi, lane, w, n0, acc);
    ln_stats(acc, l15, lhi, w, t, sred, smv);
#pragma unroll
    for (int nt = 0; nt < 4; nt++) {
        int col = n0 + nt * 16 + l15;
        float gg = out_g[col], gb = out_beta[col];
#pragma unroll
        for (int mt = 0; mt < 4; mt++)
#pragma unroll
            for (int i = 0; i < 4; i++) {
                int row = mt * 16 + lhi * 4 + i;
                if (row < G49)
                    out[((size_t)qid * G49 + row) * Cc + col] =
                        (acc[mt * 4 + nt][i] - smv[row * 2]) * smv[row * 2 + 1] * gg + gb;
            }
    }
}

// ---------------------------------------------------------------------------
extern "C" void kernel_launch(void* const* d_in, const int* in_sizes, int n_in,
                              void* d_out, int out_size, void* d_ws, size_t ws_size,
                              hipStream_t stream)
{
    const float* q       = (const float*)d_in[0];
    const float* qpe     = (const float*)d_in[1];
    const float* feat    = (const float*)d_in[2];
    const float* feat_pe = (const float*)d_in[3];
    const float* bboxes  = (const float*)d_in[4];
    const float* ge      = (const float*)d_in[5];
    const float* Wz      = (const float*)d_in[6];
    const float* Wq      = (const float*)d_in[7];
    const float* W1l     = (const float*)d_in[8];
    const float* W2l     = (const float*)d_in[9];
    const float* g1_w1   = (const float*)d_in[10];
    const float* g1_w2   = (const float*)d_in[11];
    const float* g2_w1   = (const float*)d_in[12];
    const float* g2_w2   = (const float*)d_in[13];
    const float* f1_w1   = (const float*)d_in[14];
    const float* f1_w2   = (const float*)d_in[15];
    const float* f2_w1   = (const float*)d_in[16];
    const float* f2_w2   = (const float*)d_in[17];
    const float* out_w   = (const float*)d_in[18];
    const float* bz      = (const float*)d_in[19];
    const float* bq      = (const float*)d_in[20];
    const float* b1l     = (const float*)d_in[21];
    const float* b2l     = (const float*)d_in[22];
    const float* g1_b1   = (const float*)d_in[23];
    const float* g1_b2   = (const float*)d_in[24];
    const float* g2_b1   = (const float*)d_in[25];
    const float* g2_b2   = (const float*)d_in[26];
    const float* f1_b1   = (const float*)d_in[27];
    const float* f1_b2   = (const float*)d_in[28];
    const float* f2_b1   = (const float*)d_in[29];
    const float* f2_b2   = (const float*)d_in[30];
    const float* out_b   = (const float*)d_in[31];
    const float* g1_beta = (const float*)d_in[32];
    const float* g2_beta = (const float*)d_in[33];
    const float* out_beta= (const float*)d_in[34];
    const float* g1_g    = (const float*)d_in[35];
    const float* g2_g    = (const float*)d_in[36];
    const float* out_g   = (const float*)d_in[37];

    // ws layout: total 35,734,528 B
    char* ws = (char*)d_ws;
    __hip_bfloat16* qk1  = (__hip_bfloat16*)(ws);                 // 409600
    __hip_bfloat16* qf1  = (__hip_bfloat16*)(ws + 409600);        // 409600
    __hip_bfloat16* geW1 = (__hip_bfloat16*)(ws + 819200);        // 25088
    __hip_bfloat16* gef1 = (__hip_bfloat16*)(ws + 844288);        // 25088
    __hip_bfloat16* WTf  = (__hip_bfloat16*)(ws + 869376);        // 10*131072 = 1310720
    __hip_bfloat16* fT   = (__hip_bfloat16*)(ws + 2180096);       // 16777216
    __hip_bfloat16* pT   = (__hip_bfloat16*)(ws + 18957312);      // 16777216

    prep1_kernel<<<dim3(Bb * NQ + G49), dim3(256), 0, stream>>>(
        q, qpe, ge, Wq, bq, W1l, b1l, f1_w1, f1_b1, qk1, qf1, geW1, gef1);

    wprep_kernel<<<dim3(4, 4, 10), dim3(256), 0, stream>>>(
        Wz, W2l, g2_w1, g2_w2, f2_w1, f2_w2, g1_w1, g1_w2, f1_w2, out_w, WTf);

    tr_kernel<<<dim3(1024), dim3(256), 0, stream>>>(feat, feat_pe, fT, pT);

    fused_kernel<<<dim3(Bb * NQ), dim3(256), 65536, stream>>>(
        bboxes, qk1, qf1, geW1, gef1, fT, pT, WTf,
        bz, b2l,
        g1_b1, g1_b2, g1_g, g1_beta,
        g2_b1, g2_b2, g2_g, g2_beta,
        f1_b2, f2_b1, f2_b2,
        out_b, out_g, out_beta, (float*)d_out);
}